// Round 1
// baseline (1134.467 us; speedup 1.0000x reference)
//
#include <hip/hip_runtime.h>
#include <hip/hip_bf16.h>
#include <math.h>

#define N_NODES 50000
#define N_EDGES 1600000
#define NUM_GRAPHS 512
#define HIDDEN 128
#define NUM_CLASSES 10
#define STEPS 3

// ---------------- utility kernels ----------------

__global__ void k_zero_i(int* p, int n) {
    int i = blockIdx.x * blockDim.x + threadIdx.x;
    if (i < n) p[i] = 0;
}

__global__ void k_zero_f(float* p, int n) {
    int i = blockIdx.x * blockDim.x + threadIdx.x;
    if (i < n) p[i] = 0.f;
}

// Detect int64 vs int32 storage of index inputs: OR all dwords at odd
// positions in the first 8192 dwords. int64 (values < 2^31, nonneg) -> high
// words all 0 -> flag stays 0. int32 -> odd dwords are random node ids -> !=0.
__global__ void k_detect(const int* p, int* flag, int npairs) {
    int i = blockIdx.x * blockDim.x + threadIdx.x;
    if (i < npairs) {
        int v = p[2 * i + 1];
        if (v != 0) atomicOr(flag, 1);
    }
}

__global__ void k_cvt_idx(const void* p, int* out, int n, const int* flag) {
    int i = blockIdx.x * blockDim.x + threadIdx.x;
    if (i >= n) return;
    if (*flag) out[i] = ((const int*)p)[i];
    else       out[i] = (int)(((const long long*)p)[i]);
}

__global__ void k_copy_i(const int* in, int* out, int n) {
    int i = blockIdx.x * blockDim.x + threadIdx.x;
    if (i < n) out[i] = in[i];
}

__global__ void k_hist(const int* idx, int* cnt, int n) {
    int i = blockIdx.x * blockDim.x + threadIdx.x;
    if (i < n) atomicAdd(&cnt[idx[i]], 1);
}

// Single-block exclusive scan: offs[0]=0, offs[i+1]=sum(cnt[0..i])
__global__ __launch_bounds__(1024) void k_scan(const int* cnt, int* offs, int n) {
    __shared__ int sh[1024];
    __shared__ int carry;
    int t = threadIdx.x;
    if (t == 0) { carry = 0; offs[0] = 0; }
    __syncthreads();
    for (int base = 0; base < n; base += 1024) {
        int i = base + t;
        int v = (i < n) ? cnt[i] : 0;
        sh[t] = v;
        __syncthreads();
        for (int o = 1; o < 1024; o <<= 1) {
            int tmp = (t >= o) ? sh[t - o] : 0;
            __syncthreads();
            sh[t] += tmp;
            __syncthreads();
        }
        if (i < n) offs[i + 1] = carry + sh[t];
        __syncthreads();
        if (t == 0) carry += sh[1023];
        __syncthreads();
    }
}

__global__ void k_scatter(const int* src, const int* dst, int* cursor, int* csr, int n) {
    int i = blockIdx.x * blockDim.x + threadIdx.x;
    if (i >= n) return;
    int d = dst[i];
    int pos = atomicAdd(&cursor[d], 1);
    csr[pos] = src[i];
}

__global__ void k_dinv(const int* cnt, float* dinv, int n) {
    int i = blockIdx.x * blockDim.x + threadIdx.x;
    if (i < n) dinv[i] = rsqrtf((float)(cnt[i] + 1));  // +1 self-loop
}

// ---------------- GEMM: H[n][j] = sum_k X[n][k] * W[k][j], K=N=128 ----------------
__global__ __launch_bounds__(256) void k_gemm128(const float* __restrict__ X,
                                                 const float* __restrict__ W,
                                                 float* __restrict__ H, int nrows) {
    __shared__ float xr[2][128];
    int lr = threadIdx.x >> 7;   // 0/1: which row of the pair
    int j  = threadIdx.x & 127;  // output column
    int row = blockIdx.x * 2 + lr;
    if (row < nrows) xr[lr][j] = X[row * 128 + j];
    __syncthreads();
    if (row >= nrows) return;
    float acc = 0.f;
    const float* wp = W + j;
#pragma unroll 8
    for (int k = 0; k < 128; k++) acc = fmaf(xr[lr][k], wp[k * 128], acc);
    H[row * 128 + j] = acc;
}

// ---------------- GCN aggregate: out[n] = relu(dinv[n]*(dinv[n]*H[n] + sum_e dinv[s]*H[s]) + b)
__global__ __launch_bounds__(256) void k_agg(const float* __restrict__ H,
                                             const float* __restrict__ dinv,
                                             const int* __restrict__ offs,
                                             const int* __restrict__ csr,
                                             const float* __restrict__ b,
                                             float* __restrict__ out) {
    int wave = (blockIdx.x * blockDim.x + threadIdx.x) >> 6;
    int lane = threadIdx.x & 63;
    if (wave >= N_NODES) return;
    int n = wave;
    float di = dinv[n];
    const float2* hp = (const float2*)H;
    float2 hn = hp[n * 64 + lane];
    float sx = di * hn.x, sy = di * hn.y;
    int e0 = offs[n], e1 = offs[n + 1];
    for (int j = e0; j < e1; j++) {
        int s = csr[j];
        float ds = dinv[s];
        float2 hs = hp[s * 64 + lane];
        sx = fmaf(ds, hs.x, sx);
        sy = fmaf(ds, hs.y, sy);
    }
    const float2* bp = (const float2*)b;
    float2 bb = bp[lane];
    float ox = fmaxf(fmaf(di, sx, bb.x), 0.f);
    float oy = fmaxf(fmaf(di, sy, bb.y), 0.f);
    float2 o2; o2.x = ox; o2.y = oy;
    ((float2*)out)[n * 64 + lane] = o2;
}

// ---------------- Set2Set LSTM step ----------------
// gates[b][j] = bih[j]+bhh[j] + sum_k qstar[b][k]*Wih[j][k] + sum_k h[b][k]*Whh[j][k]
#define GPB 8
__global__ __launch_bounds__(256) void k_lstm(const float* __restrict__ qstar,
                                              float* __restrict__ h, float* __restrict__ c,
                                              const float* __restrict__ Wih,
                                              const float* __restrict__ Whh,
                                              const float* __restrict__ bih,
                                              const float* __restrict__ bhh) {
    __shared__ float qs[GPB][256];
    __shared__ float hh[GPB][128];
    __shared__ float gates[GPB][512];
    int g0 = blockIdx.x * GPB;
    int t = threadIdx.x;
    for (int i = t; i < GPB * 256; i += 256) {
        int g = i >> 8, k = i & 255;
        qs[g][k] = qstar[(g0 + g) * 256 + k];
    }
    for (int i = t; i < GPB * 128; i += 256) {
        int g = i >> 7, k = i & 127;
        hh[g][k] = h[(g0 + g) * 128 + k];
    }
    __syncthreads();
    for (int jj = 0; jj < 2; jj++) {
        int j = t + jj * 256;
        float base = bih[j] + bhh[j];
        float acc[GPB];
#pragma unroll
        for (int g = 0; g < GPB; g++) acc[g] = base;
        const float* wi = Wih + j * 256;
        for (int k = 0; k < 256; k++) {
            float w = wi[k];
#pragma unroll
            for (int g = 0; g < GPB; g++) acc[g] = fmaf(w, qs[g][k], acc[g]);
        }
        const float* wh = Whh + j * 128;
        for (int k = 0; k < 128; k++) {
            float w = wh[k];
#pragma unroll
            for (int g = 0; g < GPB; g++) acc[g] = fmaf(w, hh[g][k], acc[g]);
        }
        for (int g = 0; g < GPB; g++) gates[g][j] = acc[g];
    }
    __syncthreads();
    for (int i = t; i < GPB * 128; i += 256) {
        int g = i >> 7, d = i & 127;
        int gg = g0 + g;
        float iv = gates[g][d], fv = gates[g][128 + d];
        float gv = gates[g][256 + d], ov = gates[g][384 + d];
        float si = 1.f / (1.f + expf(-iv));
        float sf = 1.f / (1.f + expf(-fv));
        float so = 1.f / (1.f + expf(-ov));
        float tg = tanhf(gv);
        float cn = sf * c[gg * 128 + d] + si * tg;
        float hn = so * tanhf(cn);
        c[gg * 128 + d] = cn;
        h[gg * 128 + d] = hn;
    }
}

// ---------------- attention: e, segment softmax, r; write qstar=[q,r] ----------------
__global__ __launch_bounds__(128) void k_attn(const float* __restrict__ X,
                                              const int* __restrict__ goff,
                                              const float* __restrict__ h,
                                              float* __restrict__ e,
                                              float* __restrict__ qstar) {
    int b = blockIdx.x;
    int t = threadIdx.x;       // 0..127
    int wv = t >> 6, l = t & 63;
    int n0 = goff[b], n1 = goff[b + 1];
    __shared__ float q[128];
    __shared__ float red[128];
    __shared__ float wm[2];
    q[t] = h[b * 128 + t];
    __syncthreads();
    const float2* qp = (const float2*)q;
    float2 q2 = qp[l];
    // pass 1: e[n] = dot(X[n], q), track max
    float mloc = -INFINITY;
    for (int n = n0 + wv; n < n1; n += 2) {
        const float2* xp = (const float2*)(X + (size_t)n * 128);
        float2 x2 = xp[l];
        float p = x2.x * q2.x + x2.y * q2.y;
#pragma unroll
        for (int o = 32; o > 0; o >>= 1) p += __shfl_xor(p, o, 64);
        if (l == 0) e[n] = p;
        mloc = fmaxf(mloc, p);
    }
    if (l == 0) wm[wv] = mloc;
    __syncthreads();
    float m = fmaxf(wm[0], wm[1]);
    if (isinf(m)) m = 0.f;   // empty segment -> reference maps -inf to 0
    // pass 2: z = exp(e - m), denom
    float s = 0.f;
    for (int n = n0 + t; n < n1; n += 128) {
        float z = expf(e[n] - m);
        e[n] = z;
        s += z;
    }
    red[t] = s;
    __syncthreads();
    for (int o = 64; o > 0; o >>= 1) {
        if (t < o) red[t] += red[t + o];
        __syncthreads();
    }
    float denom = red[0];
    float inv = (denom > 0.f) ? 1.f / denom : 0.f;
    // pass 3: r[d] = sum_n (z/denom) * X[n][d]
    float acc = 0.f;
    for (int n = n0; n < n1; n++) {
        float a = e[n] * inv;
        acc = fmaf(a, X[(size_t)n * 128 + t], acc);
    }
    qstar[b * 256 + t] = q[t];
    qstar[b * 256 + 128 + t] = acc;
}

// ---------------- final MLP head ----------------
__global__ __launch_bounds__(128) void k_mlp(const float* __restrict__ qstar,
                                             const float* __restrict__ Wl1,
                                             const float* __restrict__ bl1,
                                             const float* __restrict__ Wl2,
                                             const float* __restrict__ bl2,
                                             float* __restrict__ out) {
    int b = blockIdx.x, t = threadIdx.x;
    __shared__ float qs[256];
    __shared__ float hid[128];
    qs[t] = qstar[b * 256 + t];
    qs[128 + t] = qstar[b * 256 + 128 + t];
    __syncthreads();
    float acc = bl1[t];
#pragma unroll 4
    for (int k = 0; k < 256; k++) acc = fmaf(qs[k], Wl1[k * 128 + t], acc);
    hid[t] = fmaxf(acc, 0.f);
    __syncthreads();
    if (t < NUM_CLASSES) {
        float o = bl2[t];
#pragma unroll 4
        for (int k = 0; k < 128; k++) o = fmaf(hid[k], Wl2[k * 10 + t], o);
        out[b * 10 + t] = o;
    }
}

// ---------------- host ----------------

extern "C" void kernel_launch(void* const* d_in, const int* in_sizes, int n_in,
                              void* d_out, int out_size, void* d_ws, size_t ws_size,
                              hipStream_t stream) {
    const float* x    = (const float*)d_in[0];
    const void*  eidx = d_in[1];
    const void*  batr = d_in[2];
    const float* W1   = (const float*)d_in[3];
    const float* b1   = (const float*)d_in[4];
    const float* W2   = (const float*)d_in[5];
    const float* b2   = (const float*)d_in[6];
    const float* Wih  = (const float*)d_in[7];
    const float* Whh  = (const float*)d_in[8];
    const float* bih  = (const float*)d_in[9];
    const float* bhh  = (const float*)d_in[10];
    const float* Wl1  = (const float*)d_in[11];
    const float* bl1  = (const float*)d_in[12];
    const float* Wl2  = (const float*)d_in[13];
    const float* bl2  = (const float*)d_in[14];
    float* out = (float*)d_out;

    char* ws = (char*)d_ws;
    size_t off = 0;
    auto alloc = [&](size_t bytes) {
        size_t r = off;
        off = (off + bytes + 255) & ~(size_t)255;
        return r;
    };
    float* H       = (float*)(ws + alloc((size_t)N_NODES * 128 * 4));
    float* A       = (float*)(ws + alloc((size_t)N_NODES * 128 * 4));
    int*   csr     = (int*)(ws + alloc((size_t)N_EDGES * 4));
    int*   e32     = (int*)(ws + alloc((size_t)2 * N_EDGES * 4));
    int*   batch32 = (int*)(ws + alloc((size_t)N_NODES * 4));
    int*   cnt     = (int*)(ws + alloc((size_t)N_NODES * 4));
    int*   offs    = (int*)(ws + alloc((size_t)(N_NODES + 1) * 4));
    int*   cursor  = (int*)(ws + alloc((size_t)N_NODES * 4));
    float* dinv    = (float*)(ws + alloc((size_t)N_NODES * 4));
    float* e       = (float*)(ws + alloc((size_t)N_NODES * 4));
    int*   gcnt    = (int*)(ws + alloc((size_t)NUM_GRAPHS * 4));
    int*   goff    = (int*)(ws + alloc((size_t)(NUM_GRAPHS + 1) * 4));
    float* state   = (float*)(ws + alloc((size_t)(NUM_GRAPHS * 128 * 2 + NUM_GRAPHS * 256) * 4));
    int*   flag    = (int*)(ws + alloc(4));
    if (off > ws_size) return;  // insufficient workspace: leave output poisoned (visible failure)

    float* h_lstm = state;
    float* c_lstm = state + NUM_GRAPHS * 128;
    float* qstar  = state + NUM_GRAPHS * 256;

    int* esrc = e32;
    int* edst = e32 + N_EDGES;

    const int B = 256;
    // dtype normalize
    k_zero_i<<<1, 64, 0, stream>>>(flag, 1);
    k_detect<<<(4096 + B - 1) / B, B, 0, stream>>>((const int*)eidx, flag, 4096);
    k_cvt_idx<<<(2 * N_EDGES + B - 1) / B, B, 0, stream>>>(eidx, e32, 2 * N_EDGES, flag);
    k_cvt_idx<<<(N_NODES + B - 1) / B, B, 0, stream>>>(batr, batch32, N_NODES, flag);
    // zero accumulators
    k_zero_i<<<(N_NODES + B - 1) / B, B, 0, stream>>>(cnt, N_NODES);
    k_zero_i<<<(NUM_GRAPHS + B - 1) / B, B, 0, stream>>>(gcnt, NUM_GRAPHS);
    k_zero_f<<<(NUM_GRAPHS * 512 + B - 1) / B, B, 0, stream>>>(state, NUM_GRAPHS * 512);
    // degree + CSR
    k_hist<<<(N_EDGES + B - 1) / B, B, 0, stream>>>(edst, cnt, N_EDGES);
    k_hist<<<(N_NODES + B - 1) / B, B, 0, stream>>>(batch32, gcnt, N_NODES);
    k_scan<<<1, 1024, 0, stream>>>(cnt, offs, N_NODES);
    k_scan<<<1, 1024, 0, stream>>>(gcnt, goff, NUM_GRAPHS);
    k_copy_i<<<(N_NODES + B - 1) / B, B, 0, stream>>>(offs, cursor, N_NODES);
    k_scatter<<<(N_EDGES + B - 1) / B, B, 0, stream>>>(esrc, edst, cursor, csr, N_EDGES);
    k_dinv<<<(N_NODES + B - 1) / B, B, 0, stream>>>(cnt, dinv, N_NODES);
    // GCN conv 1
    k_gemm128<<<N_NODES / 2, 256, 0, stream>>>(x, W1, H, N_NODES);
    k_agg<<<(N_NODES + 3) / 4, 256, 0, stream>>>(H, dinv, offs, csr, b1, A);
    // GCN conv 2
    k_gemm128<<<N_NODES / 2, 256, 0, stream>>>(A, W2, H, N_NODES);
    k_agg<<<(N_NODES + 3) / 4, 256, 0, stream>>>(H, dinv, offs, csr, b2, A);
    // Set2Set
    for (int s = 0; s < STEPS; s++) {
        k_lstm<<<NUM_GRAPHS / GPB, 256, 0, stream>>>(qstar, h_lstm, c_lstm, Wih, Whh, bih, bhh);
        k_attn<<<NUM_GRAPHS, 128, 0, stream>>>(A, goff, h_lstm, e, qstar);
    }
    // head
    k_mlp<<<NUM_GRAPHS, 128, 0, stream>>>(qstar, Wl1, bl1, Wl2, bl2, out);
}

// Round 2
// 927.209 us; speedup vs baseline: 1.2235x; 1.2235x over previous
//
#include <hip/hip_runtime.h>
#include <hip/hip_bf16.h>
#include <math.h>

#define N_NODES 50000
#define N_EDGES 1600000
#define NUM_GRAPHS 512
#define HIDDEN 128
#define NUM_CLASSES 10
#define STEPS 3

// ---------------- utility kernels ----------------

__global__ void k_zero_i(int* p, int n) {
    int i = blockIdx.x * blockDim.x + threadIdx.x;
    if (i < n) p[i] = 0;
}

__global__ void k_zero_f(float* p, int n) {
    int i = blockIdx.x * blockDim.x + threadIdx.x;
    if (i < n) p[i] = 0.f;
}

// Detect int64 vs int32 storage of index inputs.
__global__ void k_detect(const int* p, int* flag, int npairs) {
    int i = blockIdx.x * blockDim.x + threadIdx.x;
    if (i < npairs) {
        int v = p[2 * i + 1];
        if (v != 0) atomicOr(flag, 1);
    }
}

__global__ void k_cvt_idx(const void* p, int* out, int n, const int* flag) {
    int i = blockIdx.x * blockDim.x + threadIdx.x;
    if (i >= n) return;
    if (*flag) out[i] = ((const int*)p)[i];
    else       out[i] = (int)(((const long long*)p)[i]);
}

__global__ void k_copy_i(const int* in, int* out, int n) {
    int i = blockIdx.x * blockDim.x + threadIdx.x;
    if (i < n) out[i] = in[i];
}

__global__ void k_hist(const int* idx, int* cnt, int n) {
    int i = blockIdx.x * blockDim.x + threadIdx.x;
    if (i < n) atomicAdd(&cnt[idx[i]], 1);
}

// Single-block exclusive scan via shfl wave-scans (3 barriers per 1024-chunk).
__global__ __launch_bounds__(1024) void k_scan(const int* cnt, int* offs, int n) {
    __shared__ int wsum[16];
    __shared__ int carry_sh;
    int t = threadIdx.x, wid = t >> 6, lane = t & 63;
    if (t == 0) { carry_sh = 0; offs[0] = 0; }
    __syncthreads();
    for (int base = 0; base < n; base += 1024) {
        int i = base + t;
        int v = (i < n) ? cnt[i] : 0;
        int x = v;
#pragma unroll
        for (int o = 1; o < 64; o <<= 1) {
            int y = __shfl_up(x, o, 64);
            if (lane >= o) x += y;
        }
        if (lane == 63) wsum[wid] = x;
        __syncthreads();
        if (wid == 0 && lane < 16) {
            int w = wsum[lane];
#pragma unroll
            for (int o = 1; o < 16; o <<= 1) {
                int y = __shfl_up(w, o, 16);
                if (lane >= o) w += y;
            }
            wsum[lane] = w;
        }
        __syncthreads();
        int add = carry_sh + (wid > 0 ? wsum[wid - 1] : 0);
        if (i < n) offs[i + 1] = add + x;
        __syncthreads();
        if (t == 0) carry_sh += wsum[15];
        __syncthreads();
    }
}

__global__ void k_scatter(const int* src, const int* dst, int* cursor, int* csr, int n) {
    int i = blockIdx.x * blockDim.x + threadIdx.x;
    if (i >= n) return;
    int d = dst[i];
    int pos = atomicAdd(&cursor[d], 1);
    csr[pos] = src[i];
}

__global__ void k_dinv(const int* cnt, float* dinv, int n) {
    int i = blockIdx.x * blockDim.x + threadIdx.x;
    if (i < n) dinv[i] = rsqrtf((float)(cnt[i] + 1));  // +1 self-loop
}

// ---------------- GEMM: H[n][j] = sum_k X[n][k] * W[k][j], K=N=128 ----------------
// 8 rows/block, 256 threads: thread owns (row r = t>>5, cols 4*(t&31)..)
__global__ __launch_bounds__(256) void k_gemm128(const float* __restrict__ X,
                                                 const float* __restrict__ W,
                                                 float* __restrict__ H, int nrows) {
    __shared__ float xr[8][128];
    int t = threadIdx.x;
    int r = t >> 5;
    int j4 = t & 31;
    int row0 = blockIdx.x * 8;
    for (int i = t; i < 8 * 128; i += 256) {
        int rr = i >> 7, cc = i & 127;
        xr[rr][cc] = X[(size_t)(row0 + rr) * 128 + cc];
    }
    __syncthreads();
    float4 acc = {0.f, 0.f, 0.f, 0.f};
    const float4* wp = (const float4*)W;
#pragma unroll 8
    for (int k = 0; k < 128; k++) {
        float4 w4 = wp[k * 32 + j4];
        float xv = xr[r][k];
        acc.x = fmaf(xv, w4.x, acc.x);
        acc.y = fmaf(xv, w4.y, acc.y);
        acc.z = fmaf(xv, w4.z, acc.z);
        acc.w = fmaf(xv, w4.w, acc.w);
    }
    ((float4*)H)[(size_t)(row0 + r) * 32 + j4] = acc;
}

// ---------------- GCN aggregate ----------------
// out[n] = relu(dinv[n]*(dinv[n]*H[n] + sum_e dinv[s]*H[s]) + b)
// One wave per node; half-waves process alternating edges; float4/lane;
// manual 4x unroll for memory-level parallelism.
__global__ __launch_bounds__(256) void k_agg(const float* __restrict__ H,
                                             const float* __restrict__ dinv,
                                             const int* __restrict__ offs,
                                             const int* __restrict__ csr,
                                             const float* __restrict__ b,
                                             float* __restrict__ out) {
    int wave = (blockIdx.x * blockDim.x + threadIdx.x) >> 6;
    int lane = threadIdx.x & 63;
    if (wave >= N_NODES) return;
    int n = wave;
    int half = lane >> 5;   // 0/1: edge subgroup
    int l = lane & 31;      // column group (float4)
    float di = dinv[n];
    const float4* hp = (const float4*)H;
    float4 acc = {0.f, 0.f, 0.f, 0.f};
    if (half == 0) {
        float4 hn = hp[(size_t)n * 32 + l];
        acc.x = di * hn.x; acc.y = di * hn.y; acc.z = di * hn.z; acc.w = di * hn.w;
    }
    int e0 = offs[n], e1 = offs[n + 1];
    int j = e0 + half;
    for (; j + 6 < e1; j += 8) {
        int s0 = csr[j], s1 = csr[j + 2], s2 = csr[j + 4], s3 = csr[j + 6];
        float d0 = dinv[s0], d1 = dinv[s1], d2 = dinv[s2], d3 = dinv[s3];
        float4 a0 = hp[(size_t)s0 * 32 + l];
        float4 a1 = hp[(size_t)s1 * 32 + l];
        float4 a2 = hp[(size_t)s2 * 32 + l];
        float4 a3 = hp[(size_t)s3 * 32 + l];
        acc.x = fmaf(d0, a0.x, acc.x); acc.y = fmaf(d0, a0.y, acc.y);
        acc.z = fmaf(d0, a0.z, acc.z); acc.w = fmaf(d0, a0.w, acc.w);
        acc.x = fmaf(d1, a1.x, acc.x); acc.y = fmaf(d1, a1.y, acc.y);
        acc.z = fmaf(d1, a1.z, acc.z); acc.w = fmaf(d1, a1.w, acc.w);
        acc.x = fmaf(d2, a2.x, acc.x); acc.y = fmaf(d2, a2.y, acc.y);
        acc.z = fmaf(d2, a2.z, acc.z); acc.w = fmaf(d2, a2.w, acc.w);
        acc.x = fmaf(d3, a3.x, acc.x); acc.y = fmaf(d3, a3.y, acc.y);
        acc.z = fmaf(d3, a3.z, acc.z); acc.w = fmaf(d3, a3.w, acc.w);
    }
    for (; j < e1; j += 2) {
        int s = csr[j];
        float ds = dinv[s];
        float4 hs = hp[(size_t)s * 32 + l];
        acc.x = fmaf(ds, hs.x, acc.x); acc.y = fmaf(ds, hs.y, acc.y);
        acc.z = fmaf(ds, hs.z, acc.z); acc.w = fmaf(ds, hs.w, acc.w);
    }
    // combine the two half-wave partials (lane <-> lane^32)
    acc.x += __shfl_xor(acc.x, 32, 64);
    acc.y += __shfl_xor(acc.y, 32, 64);
    acc.z += __shfl_xor(acc.z, 32, 64);
    acc.w += __shfl_xor(acc.w, 32, 64);
    if (half == 0) {
        const float4* bp = (const float4*)b;
        float4 bb = bp[l];
        float4 o4;
        o4.x = fmaxf(fmaf(di, acc.x, bb.x), 0.f);
        o4.y = fmaxf(fmaf(di, acc.y, bb.y), 0.f);
        o4.z = fmaxf(fmaf(di, acc.z, bb.z), 0.f);
        o4.w = fmaxf(fmaf(di, acc.w, bb.w), 0.f);
        ((float4*)out)[(size_t)n * 32 + l] = o4;
    }
}

// ---------------- Set2Set LSTM step ----------------
#define GPB 8
__global__ __launch_bounds__(256) void k_lstm(const float* __restrict__ qstar,
                                              float* __restrict__ h, float* __restrict__ c,
                                              const float* __restrict__ Wih,
                                              const float* __restrict__ Whh,
                                              const float* __restrict__ bih,
                                              const float* __restrict__ bhh) {
    __shared__ float qs[GPB][256];
    __shared__ float hh[GPB][128];
    __shared__ float gates[GPB][512];
    int g0 = blockIdx.x * GPB;
    int t = threadIdx.x;
    for (int i = t; i < GPB * 256; i += 256) {
        int g = i >> 8, k = i & 255;
        qs[g][k] = qstar[(g0 + g) * 256 + k];
    }
    for (int i = t; i < GPB * 128; i += 256) {
        int g = i >> 7, k = i & 127;
        hh[g][k] = h[(g0 + g) * 128 + k];
    }
    __syncthreads();
    for (int jj = 0; jj < 2; jj++) {
        int j = t + jj * 256;
        float base = bih[j] + bhh[j];
        float acc[GPB];
#pragma unroll
        for (int g = 0; g < GPB; g++) acc[g] = base;
        const float* wi = Wih + j * 256;
        for (int k = 0; k < 256; k++) {
            float w = wi[k];
#pragma unroll
            for (int g = 0; g < GPB; g++) acc[g] = fmaf(w, qs[g][k], acc[g]);
        }
        const float* wh = Whh + j * 128;
        for (int k = 0; k < 128; k++) {
            float w = wh[k];
#pragma unroll
            for (int g = 0; g < GPB; g++) acc[g] = fmaf(w, hh[g][k], acc[g]);
        }
        for (int g = 0; g < GPB; g++) gates[g][j] = acc[g];
    }
    __syncthreads();
    for (int i = t; i < GPB * 128; i += 256) {
        int g = i >> 7, d = i & 127;
        int gg = g0 + g;
        float iv = gates[g][d], fv = gates[g][128 + d];
        float gv = gates[g][256 + d], ov = gates[g][384 + d];
        float si = 1.f / (1.f + expf(-iv));
        float sf = 1.f / (1.f + expf(-fv));
        float so = 1.f / (1.f + expf(-ov));
        float tg = tanhf(gv);
        float cn = sf * c[gg * 128 + d] + si * tg;
        float hn = so * tanhf(cn);
        c[gg * 128 + d] = cn;
        h[gg * 128 + d] = hn;
    }
}

// ---------------- attention (256 threads / graph) ----------------
__global__ __launch_bounds__(256) void k_attn(const float* __restrict__ X,
                                              const int* __restrict__ goff,
                                              const float* __restrict__ h,
                                              float* __restrict__ e,
                                              float* __restrict__ qstar) {
    int b = blockIdx.x;
    int t = threadIdx.x;       // 0..255
    int wv = t >> 6, l = t & 63;
    int n0 = goff[b], n1 = goff[b + 1];
    __shared__ float q[128];
    __shared__ float red[256];
    __shared__ float wm[4];
    if (t < 128) q[t] = h[b * 128 + t];
    __syncthreads();
    const float2* qp = (const float2*)q;
    float2 q2 = qp[l];
    // pass 1: e[n] = dot(X[n], q), track max; 4 waves stride 4
    float mloc = -INFINITY;
    for (int n = n0 + wv; n < n1; n += 4) {
        const float2* xp = (const float2*)(X + (size_t)n * 128);
        float2 x2 = xp[l];
        float p = x2.x * q2.x + x2.y * q2.y;
#pragma unroll
        for (int o = 32; o > 0; o >>= 1) p += __shfl_xor(p, o, 64);
        if (l == 0) e[n] = p;
        mloc = fmaxf(mloc, p);
    }
    if (l == 0) wm[wv] = mloc;
    __syncthreads();
    float m = fmaxf(fmaxf(wm[0], wm[1]), fmaxf(wm[2], wm[3]));
    if (isinf(m)) m = 0.f;
    // pass 2: z = exp(e - m), denom
    float s = 0.f;
    for (int n = n0 + t; n < n1; n += 256) {
        float z = expf(e[n] - m);
        e[n] = z;
        s += z;
    }
    red[t] = s;
    __syncthreads();
    for (int o = 128; o > 0; o >>= 1) {
        if (t < o) red[t] += red[t + o];
        __syncthreads();
    }
    float denom = red[0];
    float inv = (denom > 0.f) ? 1.f / denom : 0.f;
    __syncthreads();
    // pass 3: r[d] = sum_n (z/denom) * X[n][d]; rows split between 2 groups
    int g = t >> 7, col = t & 127;
    float acc = 0.f;
    for (int n = n0 + g; n < n1; n += 2) {
        acc = fmaf(e[n] * inv, X[(size_t)n * 128 + col], acc);
    }
    red[t] = acc;
    __syncthreads();
    if (t < 128) {
        float r = red[t] + red[t + 128];
        qstar[b * 256 + t] = q[t];
        qstar[b * 256 + 128 + t] = r;
    }
}

// ---------------- final MLP head ----------------
__global__ __launch_bounds__(128) void k_mlp(const float* __restrict__ qstar,
                                             const float* __restrict__ Wl1,
                                             const float* __restrict__ bl1,
                                             const float* __restrict__ Wl2,
                                             const float* __restrict__ bl2,
                                             float* __restrict__ out) {
    int b = blockIdx.x, t = threadIdx.x;
    __shared__ float qs[256];
    __shared__ float hid[128];
    qs[t] = qstar[b * 256 + t];
    qs[128 + t] = qstar[b * 256 + 128 + t];
    __syncthreads();
    float acc = bl1[t];
#pragma unroll 4
    for (int k = 0; k < 256; k++) acc = fmaf(qs[k], Wl1[k * 128 + t], acc);
    hid[t] = fmaxf(acc, 0.f);
    __syncthreads();
    if (t < NUM_CLASSES) {
        float o = bl2[t];
#pragma unroll 4
        for (int k = 0; k < 128; k++) o = fmaf(hid[k], Wl2[k * 10 + t], o);
        out[b * 10 + t] = o;
    }
}

// ---------------- host ----------------

extern "C" void kernel_launch(void* const* d_in, const int* in_sizes, int n_in,
                              void* d_out, int out_size, void* d_ws, size_t ws_size,
                              hipStream_t stream) {
    const float* x    = (const float*)d_in[0];
    const void*  eidx = d_in[1];
    const void*  batr = d_in[2];
    const float* W1   = (const float*)d_in[3];
    const float* b1   = (const float*)d_in[4];
    const float* W2   = (const float*)d_in[5];
    const float* b2   = (const float*)d_in[6];
    const float* Wih  = (const float*)d_in[7];
    const float* Whh  = (const float*)d_in[8];
    const float* bih  = (const float*)d_in[9];
    const float* bhh  = (const float*)d_in[10];
    const float* Wl1  = (const float*)d_in[11];
    const float* bl1  = (const float*)d_in[12];
    const float* Wl2  = (const float*)d_in[13];
    const float* bl2  = (const float*)d_in[14];
    float* out = (float*)d_out;

    char* ws = (char*)d_ws;
    size_t off = 0;
    auto alloc = [&](size_t bytes) {
        size_t r = off;
        off = (off + bytes + 255) & ~(size_t)255;
        return r;
    };
    float* H       = (float*)(ws + alloc((size_t)N_NODES * 128 * 4));
    float* A       = (float*)(ws + alloc((size_t)N_NODES * 128 * 4));
    int*   csr     = (int*)(ws + alloc((size_t)N_EDGES * 4));
    int*   e32     = (int*)(ws + alloc((size_t)2 * N_EDGES * 4));
    int*   batch32 = (int*)(ws + alloc((size_t)N_NODES * 4));
    int*   cnt     = (int*)(ws + alloc((size_t)N_NODES * 4));
    int*   offs    = (int*)(ws + alloc((size_t)(N_NODES + 1) * 4));
    int*   cursor  = (int*)(ws + alloc((size_t)N_NODES * 4));
    float* dinv    = (float*)(ws + alloc((size_t)N_NODES * 4));
    float* e       = (float*)(ws + alloc((size_t)N_NODES * 4));
    int*   gcnt    = (int*)(ws + alloc((size_t)NUM_GRAPHS * 4));
    int*   goff    = (int*)(ws + alloc((size_t)(NUM_GRAPHS + 1) * 4));
    float* state   = (float*)(ws + alloc((size_t)(NUM_GRAPHS * 128 * 2 + NUM_GRAPHS * 256) * 4));
    int*   flag    = (int*)(ws + alloc(4));
    if (off > ws_size) return;

    float* h_lstm = state;
    float* c_lstm = state + NUM_GRAPHS * 128;
    float* qstar  = state + NUM_GRAPHS * 256;

    int* esrc = e32;
    int* edst = e32 + N_EDGES;

    const int B = 256;
    k_zero_i<<<1, 64, 0, stream>>>(flag, 1);
    k_detect<<<(4096 + B - 1) / B, B, 0, stream>>>((const int*)eidx, flag, 4096);
    k_cvt_idx<<<(2 * N_EDGES + B - 1) / B, B, 0, stream>>>(eidx, e32, 2 * N_EDGES, flag);
    k_cvt_idx<<<(N_NODES + B - 1) / B, B, 0, stream>>>(batr, batch32, N_NODES, flag);
    k_zero_i<<<(N_NODES + B - 1) / B, B, 0, stream>>>(cnt, N_NODES);
    k_zero_i<<<(NUM_GRAPHS + B - 1) / B, B, 0, stream>>>(gcnt, NUM_GRAPHS);
    k_zero_f<<<(NUM_GRAPHS * 512 + B - 1) / B, B, 0, stream>>>(state, NUM_GRAPHS * 512);
    k_hist<<<(N_EDGES + B - 1) / B, B, 0, stream>>>(edst, cnt, N_EDGES);
    k_hist<<<(N_NODES + B - 1) / B, B, 0, stream>>>(batch32, gcnt, N_NODES);
    k_scan<<<1, 1024, 0, stream>>>(cnt, offs, N_NODES);
    k_scan<<<1, 1024, 0, stream>>>(gcnt, goff, NUM_GRAPHS);
    k_copy_i<<<(N_NODES + B - 1) / B, B, 0, stream>>>(offs, cursor, N_NODES);
    k_scatter<<<(N_EDGES + B - 1) / B, B, 0, stream>>>(esrc, edst, cursor, csr, N_EDGES);
    k_dinv<<<(N_NODES + B - 1) / B, B, 0, stream>>>(cnt, dinv, N_NODES);
    // GCN conv 1
    k_gemm128<<<N_NODES / 8, 256, 0, stream>>>(x, W1, H, N_NODES);
    k_agg<<<(N_NODES + 3) / 4, 256, 0, stream>>>(H, dinv, offs, csr, b1, A);
    // GCN conv 2
    k_gemm128<<<N_NODES / 8, 256, 0, stream>>>(A, W2, H, N_NODES);
    k_agg<<<(N_NODES + 3) / 4, 256, 0, stream>>>(H, dinv, offs, csr, b2, A);
    // Set2Set
    for (int s = 0; s < STEPS; s++) {
        k_lstm<<<NUM_GRAPHS / GPB, 256, 0, stream>>>(qstar, h_lstm, c_lstm, Wih, Whh, bih, bhh);
        k_attn<<<NUM_GRAPHS, 256, 0, stream>>>(A, goff, h_lstm, e, qstar);
    }
    k_mlp<<<NUM_GRAPHS, 128, 0, stream>>>(qstar, Wl1, bl1, Wl2, bl2, out);
}

// Round 3
// 792.267 us; speedup vs baseline: 1.4319x; 1.1703x over previous
//
#include <hip/hip_runtime.h>
#include <hip/hip_bf16.h>
#include <math.h>

#define N_NODES 50000
#define N_EDGES 1600000
#define NUM_GRAPHS 512
#define HIDDEN 128
#define NUM_CLASSES 10
#define STEPS 3

#define NB_SHIFT 6                      // 64 nodes per bucket
#define NODES_PER_B (1 << NB_SHIFT)
#define NBUCKETS ((N_NODES + NODES_PER_B - 1) / NODES_PER_B)   // 782
#define BCAP 4096                       // mean 2048, sigma~45 -> never overflows
#define BCNT_STRIDE 16                  // one cacheline per counter

// ---------------- utility kernels ----------------

__global__ void k_zero_i(int* p, int n) {
    int i = blockIdx.x * blockDim.x + threadIdx.x;
    if (i < n) p[i] = 0;
}

__global__ void k_zero_f(float* p, int n) {
    int i = blockIdx.x * blockDim.x + threadIdx.x;
    if (i < n) p[i] = 0.f;
}

// Detect int64 vs int32 storage of index inputs.
__global__ void k_detect(const int* p, int* flag, int npairs) {
    int i = blockIdx.x * blockDim.x + threadIdx.x;
    if (i < npairs) {
        int v = p[2 * i + 1];
        if (v != 0) atomicOr(flag, 1);
    }
}

__global__ void k_cvt_idx(const void* p, int* out, int n, const int* flag) {
    int i = blockIdx.x * blockDim.x + threadIdx.x;
    if (i >= n) return;
    if (*flag) out[i] = ((const int*)p)[i];
    else       out[i] = (int)(((const long long*)p)[i]);
}

// batch is sorted: write graph start offsets by boundary detection.
__global__ void k_goff(const int* batch, int* goff, int n, int ng) {
    int i = blockIdx.x * blockDim.x + threadIdx.x;
    if (i >= n) return;
    int b = batch[i];
    int prev = (i == 0) ? -1 : batch[i - 1];
    for (int g = prev + 1; g <= b; g++) goff[g] = i;
    if (i == n - 1) {
        for (int g = b + 1; g <= ng; g++) goff[g] = n;
    }
}

// Pass 1: scatter edges into fixed-capacity dst-buckets (packed src<<6 | dst&63).
__global__ void k_bucket(const void* eidx, const int* flag, int* bcnt, int* bdata) {
    int i = blockIdx.x * blockDim.x + threadIdx.x;
    if (i >= N_EDGES) return;
    int src, dst;
    if (*flag) {
        const int* p = (const int*)eidx;
        src = p[i]; dst = p[N_EDGES + i];
    } else {
        const long long* p = (const long long*)eidx;
        src = (int)p[i]; dst = (int)p[N_EDGES + i];
    }
    int b = dst >> NB_SHIFT;
    int pos = atomicAdd(&bcnt[b * BCNT_STRIDE], 1);
    if (pos < BCAP) bdata[b * BCAP + pos] = (src << NB_SHIFT) | (dst & (NODES_PER_B - 1));
}

// Pass 2: per bucket, count per-node in LDS; write cnt + dinv dense.
__global__ __launch_bounds__(256) void k_count(const int* __restrict__ bcnt,
                                               const int* __restrict__ bdata,
                                               int* __restrict__ cnt,
                                               float* __restrict__ dinv) {
    __shared__ int lcnt[NODES_PER_B];
    int b = blockIdx.x, t = threadIdx.x;
    if (t < NODES_PER_B) lcnt[t] = 0;
    __syncthreads();
    int n = bcnt[b * BCNT_STRIDE];
    if (n > BCAP) n = BCAP;
    const int* bd = bdata + (size_t)b * BCAP;
    for (int e = t; e < n; e += 256) {
        atomicAdd(&lcnt[bd[e] & (NODES_PER_B - 1)], 1);
    }
    __syncthreads();
    int node = b * NODES_PER_B + t;
    if (t < NODES_PER_B && node < N_NODES) {
        int c = lcnt[t];
        cnt[node] = c;
        dinv[node] = rsqrtf((float)(c + 1));
    }
}

// Single-block exclusive scan via shfl wave-scans.
__global__ __launch_bounds__(1024) void k_scan(const int* cnt, int* offs, int n) {
    __shared__ int wsum[16];
    __shared__ int carry_sh;
    int t = threadIdx.x, wid = t >> 6, lane = t & 63;
    if (t == 0) { carry_sh = 0; offs[0] = 0; }
    __syncthreads();
    for (int base = 0; base < n; base += 1024) {
        int i = base + t;
        int v = (i < n) ? cnt[i] : 0;
        int x = v;
#pragma unroll
        for (int o = 1; o < 64; o <<= 1) {
            int y = __shfl_up(x, o, 64);
            if (lane >= o) x += y;
        }
        if (lane == 63) wsum[wid] = x;
        __syncthreads();
        if (wid == 0 && lane < 16) {
            int w = wsum[lane];
#pragma unroll
            for (int o = 1; o < 16; o <<= 1) {
                int y = __shfl_up(w, o, 16);
                if (lane >= o) w += y;
            }
            wsum[lane] = w;
        }
        __syncthreads();
        int add = carry_sh + (wid > 0 ? wsum[wid - 1] : 0);
        if (i < n) offs[i + 1] = add + x;
        __syncthreads();
        if (t == 0) carry_sh += wsum[15];
        __syncthreads();
    }
}

// Pass 3: per bucket, scatter src ids into the bucket's contiguous csr segment.
__global__ __launch_bounds__(256) void k_lscatter(const int* __restrict__ bcnt,
                                                  const int* __restrict__ bdata,
                                                  const int* __restrict__ offs,
                                                  int* __restrict__ csr) {
    __shared__ int lcnt[NODES_PER_B];
    __shared__ int loffs[NODES_PER_B];
    int b = blockIdx.x, t = threadIdx.x;
    if (t < NODES_PER_B) {
        lcnt[t] = 0;
        int node = b * NODES_PER_B + t;
        loffs[t] = (node < N_NODES) ? offs[node] : 0;
    }
    __syncthreads();
    int n = bcnt[b * BCNT_STRIDE];
    if (n > BCAP) n = BCAP;
    const int* bd = bdata + (size_t)b * BCAP;
    for (int e = t; e < n; e += 256) {
        int pack = bd[e];
        int slot = pack & (NODES_PER_B - 1);
        int pos = atomicAdd(&lcnt[slot], 1);
        csr[loffs[slot] + pos] = pack >> NB_SHIFT;
    }
}

// ---------------- GEMM: H[n][j] = sum_k X[n][k] * W[k][j], K=N=128 ----------------
__global__ __launch_bounds__(256) void k_gemm128(const float* __restrict__ X,
                                                 const float* __restrict__ W,
                                                 float* __restrict__ H, int nrows) {
    __shared__ float xr[8][128];
    int t = threadIdx.x;
    int r = t >> 5;
    int j4 = t & 31;
    int row0 = blockIdx.x * 8;
    for (int i = t; i < 8 * 128; i += 256) {
        int rr = i >> 7, cc = i & 127;
        xr[rr][cc] = X[(size_t)(row0 + rr) * 128 + cc];
    }
    __syncthreads();
    float4 acc = {0.f, 0.f, 0.f, 0.f};
    const float4* wp = (const float4*)W;
#pragma unroll 8
    for (int k = 0; k < 128; k++) {
        float4 w4 = wp[k * 32 + j4];
        float xv = xr[r][k];
        acc.x = fmaf(xv, w4.x, acc.x);
        acc.y = fmaf(xv, w4.y, acc.y);
        acc.z = fmaf(xv, w4.z, acc.z);
        acc.w = fmaf(xv, w4.w, acc.w);
    }
    ((float4*)H)[(size_t)(row0 + r) * 32 + j4] = acc;
}

// ---------------- GCN aggregate ----------------
__global__ __launch_bounds__(256) void k_agg(const float* __restrict__ H,
                                             const float* __restrict__ dinv,
                                             const int* __restrict__ offs,
                                             const int* __restrict__ csr,
                                             const float* __restrict__ b,
                                             float* __restrict__ out) {
    int wave = (blockIdx.x * blockDim.x + threadIdx.x) >> 6;
    int lane = threadIdx.x & 63;
    if (wave >= N_NODES) return;
    int n = wave;
    int half = lane >> 5;
    int l = lane & 31;
    float di = dinv[n];
    const float4* hp = (const float4*)H;
    float4 acc = {0.f, 0.f, 0.f, 0.f};
    if (half == 0) {
        float4 hn = hp[(size_t)n * 32 + l];
        acc.x = di * hn.x; acc.y = di * hn.y; acc.z = di * hn.z; acc.w = di * hn.w;
    }
    int e0 = offs[n], e1 = offs[n + 1];
    int j = e0 + half;
    for (; j + 6 < e1; j += 8) {
        int s0 = csr[j], s1 = csr[j + 2], s2 = csr[j + 4], s3 = csr[j + 6];
        float d0 = dinv[s0], d1 = dinv[s1], d2 = dinv[s2], d3 = dinv[s3];
        float4 a0 = hp[(size_t)s0 * 32 + l];
        float4 a1 = hp[(size_t)s1 * 32 + l];
        float4 a2 = hp[(size_t)s2 * 32 + l];
        float4 a3 = hp[(size_t)s3 * 32 + l];
        acc.x = fmaf(d0, a0.x, acc.x); acc.y = fmaf(d0, a0.y, acc.y);
        acc.z = fmaf(d0, a0.z, acc.z); acc.w = fmaf(d0, a0.w, acc.w);
        acc.x = fmaf(d1, a1.x, acc.x); acc.y = fmaf(d1, a1.y, acc.y);
        acc.z = fmaf(d1, a1.z, acc.z); acc.w = fmaf(d1, a1.w, acc.w);
        acc.x = fmaf(d2, a2.x, acc.x); acc.y = fmaf(d2, a2.y, acc.y);
        acc.z = fmaf(d2, a2.z, acc.z); acc.w = fmaf(d2, a2.w, acc.w);
        acc.x = fmaf(d3, a3.x, acc.x); acc.y = fmaf(d3, a3.y, acc.y);
        acc.z = fmaf(d3, a3.z, acc.z); acc.w = fmaf(d3, a3.w, acc.w);
    }
    for (; j < e1; j += 2) {
        int s = csr[j];
        float ds = dinv[s];
        float4 hs = hp[(size_t)s * 32 + l];
        acc.x = fmaf(ds, hs.x, acc.x); acc.y = fmaf(ds, hs.y, acc.y);
        acc.z = fmaf(ds, hs.z, acc.z); acc.w = fmaf(ds, hs.w, acc.w);
    }
    acc.x += __shfl_xor(acc.x, 32, 64);
    acc.y += __shfl_xor(acc.y, 32, 64);
    acc.z += __shfl_xor(acc.z, 32, 64);
    acc.w += __shfl_xor(acc.w, 32, 64);
    if (half == 0) {
        const float4* bp = (const float4*)b;
        float4 bb = bp[l];
        float4 o4;
        o4.x = fmaxf(fmaf(di, acc.x, bb.x), 0.f);
        o4.y = fmaxf(fmaf(di, acc.y, bb.y), 0.f);
        o4.z = fmaxf(fmaf(di, acc.z, bb.z), 0.f);
        o4.w = fmaxf(fmaf(di, acc.w, bb.w), 0.f);
        ((float4*)out)[(size_t)n * 32 + l] = o4;
    }
}

// ---------------- Set2Set LSTM step ----------------
#define GPB 8
__global__ __launch_bounds__(256) void k_lstm(const float* __restrict__ qstar,
                                              float* __restrict__ h, float* __restrict__ c,
                                              const float* __restrict__ Wih,
                                              const float* __restrict__ Whh,
                                              const float* __restrict__ bih,
                                              const float* __restrict__ bhh) {
    __shared__ float qs[GPB][256];
    __shared__ float hh[GPB][128];
    __shared__ float gates[GPB][512];
    int g0 = blockIdx.x * GPB;
    int t = threadIdx.x;
    for (int i = t; i < GPB * 256; i += 256) {
        int g = i >> 8, k = i & 255;
        qs[g][k] = qstar[(g0 + g) * 256 + k];
    }
    for (int i = t; i < GPB * 128; i += 256) {
        int g = i >> 7, k = i & 127;
        hh[g][k] = h[(g0 + g) * 128 + k];
    }
    __syncthreads();
    for (int jj = 0; jj < 2; jj++) {
        int j = t + jj * 256;
        float base = bih[j] + bhh[j];
        float acc[GPB];
#pragma unroll
        for (int g = 0; g < GPB; g++) acc[g] = base;
        const float* wi = Wih + j * 256;
        for (int k = 0; k < 256; k++) {
            float w = wi[k];
#pragma unroll
            for (int g = 0; g < GPB; g++) acc[g] = fmaf(w, qs[g][k], acc[g]);
        }
        const float* wh = Whh + j * 128;
        for (int k = 0; k < 128; k++) {
            float w = wh[k];
#pragma unroll
            for (int g = 0; g < GPB; g++) acc[g] = fmaf(w, hh[g][k], acc[g]);
        }
        for (int g = 0; g < GPB; g++) gates[g][j] = acc[g];
    }
    __syncthreads();
    for (int i = t; i < GPB * 128; i += 256) {
        int g = i >> 7, d = i & 127;
        int gg = g0 + g;
        float iv = gates[g][d], fv = gates[g][128 + d];
        float gv = gates[g][256 + d], ov = gates[g][384 + d];
        float si = 1.f / (1.f + expf(-iv));
        float sf = 1.f / (1.f + expf(-fv));
        float so = 1.f / (1.f + expf(-ov));
        float tg = tanhf(gv);
        float cn = sf * c[gg * 128 + d] + si * tg;
        float hn = so * tanhf(cn);
        c[gg * 128 + d] = cn;
        h[gg * 128 + d] = hn;
    }
}

// ---------------- attention (256 threads / graph) ----------------
__global__ __launch_bounds__(256) void k_attn(const float* __restrict__ X,
                                              const int* __restrict__ goff,
                                              const float* __restrict__ h,
                                              float* __restrict__ e,
                                              float* __restrict__ qstar) {
    int b = blockIdx.x;
    int t = threadIdx.x;
    int wv = t >> 6, l = t & 63;
    int n0 = goff[b], n1 = goff[b + 1];
    __shared__ float q[128];
    __shared__ float red[256];
    __shared__ float wm[4];
    if (t < 128) q[t] = h[b * 128 + t];
    __syncthreads();
    const float2* qp = (const float2*)q;
    float2 q2 = qp[l];
    float mloc = -INFINITY;
    for (int n = n0 + wv; n < n1; n += 4) {
        const float2* xp = (const float2*)(X + (size_t)n * 128);
        float2 x2 = xp[l];
        float p = x2.x * q2.x + x2.y * q2.y;
#pragma unroll
        for (int o = 32; o > 0; o >>= 1) p += __shfl_xor(p, o, 64);
        if (l == 0) e[n] = p;
        mloc = fmaxf(mloc, p);
    }
    if (l == 0) wm[wv] = mloc;
    __syncthreads();
    float m = fmaxf(fmaxf(wm[0], wm[1]), fmaxf(wm[2], wm[3]));
    if (isinf(m)) m = 0.f;
    float s = 0.f;
    for (int n = n0 + t; n < n1; n += 256) {
        float z = expf(e[n] - m);
        e[n] = z;
        s += z;
    }
    red[t] = s;
    __syncthreads();
    for (int o = 128; o > 0; o >>= 1) {
        if (t < o) red[t] += red[t + o];
        __syncthreads();
    }
    float denom = red[0];
    float inv = (denom > 0.f) ? 1.f / denom : 0.f;
    __syncthreads();
    int g = t >> 7, col = t & 127;
    float acc = 0.f;
    for (int n = n0 + g; n < n1; n += 2) {
        acc = fmaf(e[n] * inv, X[(size_t)n * 128 + col], acc);
    }
    red[t] = acc;
    __syncthreads();
    if (t < 128) {
        float r = red[t] + red[t + 128];
        qstar[b * 256 + t] = q[t];
        qstar[b * 256 + 128 + t] = r;
    }
}

// ---------------- final MLP head ----------------
__global__ __launch_bounds__(128) void k_mlp(const float* __restrict__ qstar,
                                             const float* __restrict__ Wl1,
                                             const float* __restrict__ bl1,
                                             const float* __restrict__ Wl2,
                                             const float* __restrict__ bl2,
                                             float* __restrict__ out) {
    int b = blockIdx.x, t = threadIdx.x;
    __shared__ float qs[256];
    __shared__ float hid[128];
    qs[t] = qstar[b * 256 + t];
    qs[128 + t] = qstar[b * 256 + 128 + t];
    __syncthreads();
    float acc = bl1[t];
#pragma unroll 4
    for (int k = 0; k < 256; k++) acc = fmaf(qs[k], Wl1[k * 128 + t], acc);
    hid[t] = fmaxf(acc, 0.f);
    __syncthreads();
    if (t < NUM_CLASSES) {
        float o = bl2[t];
#pragma unroll 4
        for (int k = 0; k < 128; k++) o = fmaf(hid[k], Wl2[k * 10 + t], o);
        out[b * 10 + t] = o;
    }
}

// ---------------- host ----------------

extern "C" void kernel_launch(void* const* d_in, const int* in_sizes, int n_in,
                              void* d_out, int out_size, void* d_ws, size_t ws_size,
                              hipStream_t stream) {
    const float* x    = (const float*)d_in[0];
    const void*  eidx = d_in[1];
    const void*  batr = d_in[2];
    const float* W1   = (const float*)d_in[3];
    const float* b1   = (const float*)d_in[4];
    const float* W2   = (const float*)d_in[5];
    const float* b2   = (const float*)d_in[6];
    const float* Wih  = (const float*)d_in[7];
    const float* Whh  = (const float*)d_in[8];
    const float* bih  = (const float*)d_in[9];
    const float* bhh  = (const float*)d_in[10];
    const float* Wl1  = (const float*)d_in[11];
    const float* bl1  = (const float*)d_in[12];
    const float* Wl2  = (const float*)d_in[13];
    const float* bl2  = (const float*)d_in[14];
    float* out = (float*)d_out;

    char* ws = (char*)d_ws;
    size_t off = 0;
    auto alloc = [&](size_t bytes) {
        size_t r = off;
        off = (off + bytes + 255) & ~(size_t)255;
        return r;
    };
    float* H       = (float*)(ws + alloc((size_t)N_NODES * 128 * 4));
    float* A       = (float*)(ws + alloc((size_t)N_NODES * 128 * 4));
    int*   csr     = (int*)(ws + alloc((size_t)N_EDGES * 4));
    int*   bdata   = (int*)(ws + alloc((size_t)NBUCKETS * BCAP * 4));
    int*   bcnt    = (int*)(ws + alloc((size_t)NBUCKETS * BCNT_STRIDE * 4));
    int*   batch32 = (int*)(ws + alloc((size_t)N_NODES * 4));
    int*   cnt     = (int*)(ws + alloc((size_t)N_NODES * 4));
    int*   offs    = (int*)(ws + alloc((size_t)(N_NODES + 1) * 4));
    float* dinv    = (float*)(ws + alloc((size_t)N_NODES * 4));
    float* e       = (float*)(ws + alloc((size_t)N_NODES * 4));
    int*   goff    = (int*)(ws + alloc((size_t)(NUM_GRAPHS + 1) * 4));
    float* state   = (float*)(ws + alloc((size_t)(NUM_GRAPHS * 128 * 2 + NUM_GRAPHS * 256) * 4));
    int*   flag    = (int*)(ws + alloc(4));
    if (off > ws_size) return;

    float* h_lstm = state;
    float* c_lstm = state + NUM_GRAPHS * 128;
    float* qstar  = state + NUM_GRAPHS * 256;

    const int B = 256;
    k_zero_i<<<1, 64, 0, stream>>>(flag, 1);
    k_detect<<<(4096 + B - 1) / B, B, 0, stream>>>((const int*)eidx, flag, 4096);
    k_zero_i<<<(NBUCKETS * BCNT_STRIDE + B - 1) / B, B, 0, stream>>>(bcnt, NBUCKETS * BCNT_STRIDE);
    k_zero_f<<<(NUM_GRAPHS * 512 + B - 1) / B, B, 0, stream>>>(state, NUM_GRAPHS * 512);
    k_cvt_idx<<<(N_NODES + B - 1) / B, B, 0, stream>>>(batr, batch32, N_NODES, flag);
    // CSR build (bucketed, dense writes)
    k_bucket<<<(N_EDGES + B - 1) / B, B, 0, stream>>>(eidx, flag, bcnt, bdata);
    k_goff<<<(N_NODES + B - 1) / B, B, 0, stream>>>(batch32, goff, N_NODES, NUM_GRAPHS);
    k_count<<<NBUCKETS, 256, 0, stream>>>(bcnt, bdata, cnt, dinv);
    k_scan<<<1, 1024, 0, stream>>>(cnt, offs, N_NODES);
    k_lscatter<<<NBUCKETS, 256, 0, stream>>>(bcnt, bdata, offs, csr);
    // GCN conv 1
    k_gemm128<<<N_NODES / 8, 256, 0, stream>>>(x, W1, H, N_NODES);
    k_agg<<<(N_NODES + 3) / 4, 256, 0, stream>>>(H, dinv, offs, csr, b1, A);
    // GCN conv 2
    k_gemm128<<<N_NODES / 8, 256, 0, stream>>>(A, W2, H, N_NODES);
    k_agg<<<(N_NODES + 3) / 4, 256, 0, stream>>>(H, dinv, offs, csr, b2, A);
    // Set2Set
    for (int s = 0; s < STEPS; s++) {
        k_lstm<<<NUM_GRAPHS / GPB, 256, 0, stream>>>(qstar, h_lstm, c_lstm, Wih, Whh, bih, bhh);
        k_attn<<<NUM_GRAPHS, 256, 0, stream>>>(A, goff, h_lstm, e, qstar);
    }
    k_mlp<<<NUM_GRAPHS, 128, 0, stream>>>(qstar, Wl1, bl1, Wl2, bl2, out);
}

// Round 4
// 571.481 us; speedup vs baseline: 1.9851x; 1.3863x over previous
//
#include <hip/hip_runtime.h>
#include <hip/hip_bf16.h>
#include <math.h>

#define N_NODES 50000
#define N_EDGES 1600000
#define NUM_GRAPHS 512
#define HIDDEN 128
#define NUM_CLASSES 10
#define STEPS 3

#define NB_SHIFT 6                      // 64 nodes per bucket
#define NODES_PER_B (1 << NB_SHIFT)
#define NBUCKETS ((N_NODES + NODES_PER_B - 1) / NODES_PER_B)   // 782
#define BCAP 4096                       // mean 2048, sigma~45 -> never overflows
#define BCNT_STRIDE 16                  // one cacheline per counter

__device__ inline float bf2f(unsigned short h) {
    union { unsigned int u; float f; } v; v.u = ((unsigned int)h) << 16; return v.f;
}
__device__ inline unsigned short f2bf(float f) {
    union { float f; unsigned int u; } v; v.f = f;
    unsigned int r = (v.u + 0x7FFFu + ((v.u >> 16) & 1u)) >> 16;
    return (unsigned short)r;
}

// ---------------- utility kernels ----------------

// Detect int64 vs int32 storage of index inputs.
__global__ void k_detect(const int* p, int* flag, int npairs) {
    int i = blockIdx.x * blockDim.x + threadIdx.x;
    if (i < npairs) {
        int v = p[2 * i + 1];
        if (v != 0) atomicOr(flag, 1);
    }
}

__global__ void k_cvt_idx(const void* p, int* out, int n, const int* flag) {
    int i = blockIdx.x * blockDim.x + threadIdx.x;
    if (i >= n) return;
    if (*flag) out[i] = ((const int*)p)[i];
    else       out[i] = (int)(((const long long*)p)[i]);
}

// batch is sorted: write graph start offsets by boundary detection.
__global__ void k_goff(const int* batch, int* goff, int n, int ng) {
    int i = blockIdx.x * blockDim.x + threadIdx.x;
    if (i >= n) return;
    int b = batch[i];
    int prev = (i == 0) ? -1 : batch[i - 1];
    for (int g = prev + 1; g <= b; g++) goff[g] = i;
    if (i == n - 1) {
        for (int g = b + 1; g <= ng; g++) goff[g] = n;
    }
}

// Pass 1: scatter edges into fixed-capacity dst-buckets (packed src<<6 | dst&63).
__global__ void k_bucket(const void* eidx, const int* flag, int* bcnt, int* bdata) {
    int i = blockIdx.x * blockDim.x + threadIdx.x;
    if (i >= N_EDGES) return;
    int src, dst;
    if (*flag) {
        const int* p = (const int*)eidx;
        src = p[i]; dst = p[N_EDGES + i];
    } else {
        const long long* p = (const long long*)eidx;
        src = (int)p[i]; dst = (int)p[N_EDGES + i];
    }
    int b = dst >> NB_SHIFT;
    int pos = atomicAdd(&bcnt[b * BCNT_STRIDE], 1);
    if (pos < BCAP) bdata[b * BCAP + pos] = (src << NB_SHIFT) | (dst & (NODES_PER_B - 1));
}

// Pass 2: per bucket, count per-node in LDS; write cnt + dinv dense.
__global__ __launch_bounds__(256) void k_count(const int* __restrict__ bcnt,
                                               const int* __restrict__ bdata,
                                               int* __restrict__ cnt,
                                               float* __restrict__ dinv) {
    __shared__ int lcnt[NODES_PER_B];
    int b = blockIdx.x, t = threadIdx.x;
    if (t < NODES_PER_B) lcnt[t] = 0;
    __syncthreads();
    int n = bcnt[b * BCNT_STRIDE];
    if (n > BCAP) n = BCAP;
    const int* bd = bdata + (size_t)b * BCAP;
    for (int e = t; e < n; e += 256) {
        atomicAdd(&lcnt[bd[e] & (NODES_PER_B - 1)], 1);
    }
    __syncthreads();
    int node = b * NODES_PER_B + t;
    if (t < NODES_PER_B && node < N_NODES) {
        int c = lcnt[t];
        cnt[node] = c;
        dinv[node] = rsqrtf((float)(c + 1));
    }
}

// Single-block exclusive scan via shfl wave-scans.
__global__ __launch_bounds__(1024) void k_scan(const int* cnt, int* offs, int n) {
    __shared__ int wsum[16];
    __shared__ int carry_sh;
    int t = threadIdx.x, wid = t >> 6, lane = t & 63;
    if (t == 0) { carry_sh = 0; offs[0] = 0; }
    __syncthreads();
    for (int base = 0; base < n; base += 1024) {
        int i = base + t;
        int v = (i < n) ? cnt[i] : 0;
        int x = v;
#pragma unroll
        for (int o = 1; o < 64; o <<= 1) {
            int y = __shfl_up(x, o, 64);
            if (lane >= o) x += y;
        }
        if (lane == 63) wsum[wid] = x;
        __syncthreads();
        if (wid == 0 && lane < 16) {
            int w = wsum[lane];
#pragma unroll
            for (int o = 1; o < 16; o <<= 1) {
                int y = __shfl_up(w, o, 16);
                if (lane >= o) w += y;
            }
            wsum[lane] = w;
        }
        __syncthreads();
        int add = carry_sh + (wid > 0 ? wsum[wid - 1] : 0);
        if (i < n) offs[i + 1] = add + x;
        __syncthreads();
        if (t == 0) carry_sh += wsum[15];
        __syncthreads();
    }
}

// Pass 3: per bucket, scatter src ids into the bucket's contiguous csr segment.
__global__ __launch_bounds__(256) void k_lscatter(const int* __restrict__ bcnt,
                                                  const int* __restrict__ bdata,
                                                  const int* __restrict__ offs,
                                                  int* __restrict__ csr) {
    __shared__ int lcnt[NODES_PER_B];
    __shared__ int loffs[NODES_PER_B];
    int b = blockIdx.x, t = threadIdx.x;
    if (t < NODES_PER_B) {
        lcnt[t] = 0;
        int node = b * NODES_PER_B + t;
        loffs[t] = (node < N_NODES) ? offs[node] : 0;
    }
    __syncthreads();
    int n = bcnt[b * BCNT_STRIDE];
    if (n > BCAP) n = BCAP;
    const int* bd = bdata + (size_t)b * BCAP;
    for (int e = t; e < n; e += 256) {
        int pack = bd[e];
        int slot = pack & (NODES_PER_B - 1);
        int pos = atomicAdd(&lcnt[slot], 1);
        csr[loffs[slot] + pos] = pack >> NB_SHIFT;
    }
}

// ---------------- GEMM: H[n][j] = sum_k X[n][k] * W[k][j], K=N=128 ----------------
// 64 rows/block, 256 threads; thread owns 8 rows x 4 cols (acc = 8 x float4).
// Also emits a bf16 copy of H for the aggregation gather.
__global__ __launch_bounds__(256) void k_gemm64(const float* __restrict__ X,
                                                const float* __restrict__ W,
                                                float* __restrict__ H,
                                                unsigned short* __restrict__ Hb,
                                                int nrows) {
    __shared__ float xs[64][128];
    int t = threadIdx.x;
    int a = t >> 5;          // row group: rows 8a..8a+7
    int j4 = t & 31;         // float4 column group
    int row0 = blockIdx.x * 64;
    for (int i = t; i < 64 * 32; i += 256) {
        int rr = i >> 5;
        int c4 = i & 31;
        int r = row0 + rr; if (r >= nrows) r = nrows - 1;
        ((float4*)xs[rr])[c4] = ((const float4*)X)[(size_t)r * 32 + c4];
    }
    __syncthreads();
    float4 acc[8];
#pragma unroll
    for (int i = 0; i < 8; i++) acc[i] = {0.f, 0.f, 0.f, 0.f};
    const float4* wp = (const float4*)W;
#pragma unroll 4
    for (int k = 0; k < 128; k++) {
        float4 w4 = wp[k * 32 + j4];
#pragma unroll
        for (int i = 0; i < 8; i++) {
            float xv = xs[8 * a + i][k];
            acc[i].x = fmaf(xv, w4.x, acc[i].x);
            acc[i].y = fmaf(xv, w4.y, acc[i].y);
            acc[i].z = fmaf(xv, w4.z, acc[i].z);
            acc[i].w = fmaf(xv, w4.w, acc[i].w);
        }
    }
#pragma unroll
    for (int i = 0; i < 8; i++) {
        int r = row0 + 8 * a + i;
        if (r < nrows) {
            ((float4*)H)[(size_t)r * 32 + j4] = acc[i];
            ushort4 b4;
            b4.x = f2bf(acc[i].x); b4.y = f2bf(acc[i].y);
            b4.z = f2bf(acc[i].z); b4.w = f2bf(acc[i].w);
            ((ushort4*)Hb)[(size_t)r * 32 + j4] = b4;
        }
    }
}

// ---------------- GCN aggregate ----------------
// out[n] = relu(dinv[n]*(dinv[n]*H[n] + sum_e dinv[s]*Hb[s]) + b)
// Neighbor gather reads the bf16 copy (half the bytes); self-term fp32.
__global__ __launch_bounds__(256) void k_agg(const float* __restrict__ H,
                                             const unsigned short* __restrict__ Hb,
                                             const float* __restrict__ dinv,
                                             const int* __restrict__ offs,
                                             const int* __restrict__ csr,
                                             const float* __restrict__ b,
                                             float* __restrict__ out) {
    int wave = (blockIdx.x * blockDim.x + threadIdx.x) >> 6;
    int lane = threadIdx.x & 63;
    if (wave >= N_NODES) return;
    int n = wave;
    int half = lane >> 5;
    int l = lane & 31;
    float di = dinv[n];
    const ushort4* hbp = (const ushort4*)Hb;
    float4 acc = {0.f, 0.f, 0.f, 0.f};
    if (half == 0) {
        float4 hn = ((const float4*)H)[(size_t)n * 32 + l];
        acc.x = di * hn.x; acc.y = di * hn.y; acc.z = di * hn.z; acc.w = di * hn.w;
    }
    int e0 = offs[n], e1 = offs[n + 1];
    int j = e0 + half;
    for (; j + 6 < e1; j += 8) {
        int s0 = csr[j], s1 = csr[j + 2], s2 = csr[j + 4], s3 = csr[j + 6];
        float d0 = dinv[s0], d1 = dinv[s1], d2 = dinv[s2], d3 = dinv[s3];
        ushort4 a0 = hbp[(size_t)s0 * 32 + l];
        ushort4 a1 = hbp[(size_t)s1 * 32 + l];
        ushort4 a2 = hbp[(size_t)s2 * 32 + l];
        ushort4 a3 = hbp[(size_t)s3 * 32 + l];
        acc.x = fmaf(d0, bf2f(a0.x), acc.x); acc.y = fmaf(d0, bf2f(a0.y), acc.y);
        acc.z = fmaf(d0, bf2f(a0.z), acc.z); acc.w = fmaf(d0, bf2f(a0.w), acc.w);
        acc.x = fmaf(d1, bf2f(a1.x), acc.x); acc.y = fmaf(d1, bf2f(a1.y), acc.y);
        acc.z = fmaf(d1, bf2f(a1.z), acc.z); acc.w = fmaf(d1, bf2f(a1.w), acc.w);
        acc.x = fmaf(d2, bf2f(a2.x), acc.x); acc.y = fmaf(d2, bf2f(a2.y), acc.y);
        acc.z = fmaf(d2, bf2f(a2.z), acc.z); acc.w = fmaf(d2, bf2f(a2.w), acc.w);
        acc.x = fmaf(d3, bf2f(a3.x), acc.x); acc.y = fmaf(d3, bf2f(a3.y), acc.y);
        acc.z = fmaf(d3, bf2f(a3.z), acc.z); acc.w = fmaf(d3, bf2f(a3.w), acc.w);
    }
    for (; j < e1; j += 2) {
        int s = csr[j];
        float ds = dinv[s];
        ushort4 hs = hbp[(size_t)s * 32 + l];
        acc.x = fmaf(ds, bf2f(hs.x), acc.x); acc.y = fmaf(ds, bf2f(hs.y), acc.y);
        acc.z = fmaf(ds, bf2f(hs.z), acc.z); acc.w = fmaf(ds, bf2f(hs.w), acc.w);
    }
    acc.x += __shfl_xor(acc.x, 32, 64);
    acc.y += __shfl_xor(acc.y, 32, 64);
    acc.z += __shfl_xor(acc.z, 32, 64);
    acc.w += __shfl_xor(acc.w, 32, 64);
    if (half == 0) {
        const float4* bp = (const float4*)b;
        float4 bb = bp[l];
        float4 o4;
        o4.x = fmaxf(fmaf(di, acc.x, bb.x), 0.f);
        o4.y = fmaxf(fmaf(di, acc.y, bb.y), 0.f);
        o4.z = fmaxf(fmaf(di, acc.z, bb.z), 0.f);
        o4.w = fmaxf(fmaf(di, acc.w, bb.w), 0.f);
        ((float4*)out)[(size_t)n * 32 + l] = o4;
    }
}

// ---------------- Set2Set LSTM step ----------------
#define GPB 8
__global__ __launch_bounds__(256) void k_lstm(const float* __restrict__ qstar,
                                              float* __restrict__ h, float* __restrict__ c,
                                              const float* __restrict__ Wih,
                                              const float* __restrict__ Whh,
                                              const float* __restrict__ bih,
                                              const float* __restrict__ bhh) {
    __shared__ float qs[GPB][256];
    __shared__ float hh[GPB][128];
    __shared__ float gates[GPB][512];
    int g0 = blockIdx.x * GPB;
    int t = threadIdx.x;
    for (int i = t; i < GPB * 256; i += 256) {
        int g = i >> 8, k = i & 255;
        qs[g][k] = qstar[(g0 + g) * 256 + k];
    }
    for (int i = t; i < GPB * 128; i += 256) {
        int g = i >> 7, k = i & 127;
        hh[g][k] = h[(g0 + g) * 128 + k];
    }
    __syncthreads();
    for (int jj = 0; jj < 2; jj++) {
        int j = t + jj * 256;
        float base = bih[j] + bhh[j];
        float acc[GPB];
#pragma unroll
        for (int g = 0; g < GPB; g++) acc[g] = base;
        const float* wi = Wih + j * 256;
        for (int k = 0; k < 256; k++) {
            float w = wi[k];
#pragma unroll
            for (int g = 0; g < GPB; g++) acc[g] = fmaf(w, qs[g][k], acc[g]);
        }
        const float* wh = Whh + j * 128;
        for (int k = 0; k < 128; k++) {
            float w = wh[k];
#pragma unroll
            for (int g = 0; g < GPB; g++) acc[g] = fmaf(w, hh[g][k], acc[g]);
        }
        for (int g = 0; g < GPB; g++) gates[g][j] = acc[g];
    }
    __syncthreads();
    for (int i = t; i < GPB * 128; i += 256) {
        int g = i >> 7, d = i & 127;
        int gg = g0 + g;
        float iv = gates[g][d], fv = gates[g][128 + d];
        float gv = gates[g][256 + d], ov = gates[g][384 + d];
        float si = 1.f / (1.f + expf(-iv));
        float sf = 1.f / (1.f + expf(-fv));
        float so = 1.f / (1.f + expf(-ov));
        float tg = tanhf(gv);
        float cn = sf * c[gg * 128 + d] + si * tg;
        float hn = so * tanhf(cn);
        c[gg * 128 + d] = cn;
        h[gg * 128 + d] = hn;
    }
}

// ---------------- attention (256 threads / graph) ----------------
__global__ __launch_bounds__(256) void k_attn(const float* __restrict__ X,
                                              const int* __restrict__ goff,
                                              const float* __restrict__ h,
                                              float* __restrict__ e,
                                              float* __restrict__ qstar) {
    int b = blockIdx.x;
    int t = threadIdx.x;
    int wv = t >> 6, l = t & 63;
    int n0 = goff[b], n1 = goff[b + 1];
    __shared__ float q[128];
    __shared__ float red[256];
    __shared__ float wm[4];
    if (t < 128) q[t] = h[b * 128 + t];
    __syncthreads();
    const float2* qp = (const float2*)q;
    float2 q2 = qp[l];
    float mloc = -INFINITY;
    for (int n = n0 + wv; n < n1; n += 4) {
        const float2* xp = (const float2*)(X + (size_t)n * 128);
        float2 x2 = xp[l];
        float p = x2.x * q2.x + x2.y * q2.y;
#pragma unroll
        for (int o = 32; o > 0; o >>= 1) p += __shfl_xor(p, o, 64);
        if (l == 0) e[n] = p;
        mloc = fmaxf(mloc, p);
    }
    if (l == 0) wm[wv] = mloc;
    __syncthreads();
    float m = fmaxf(fmaxf(wm[0], wm[1]), fmaxf(wm[2], wm[3]));
    if (isinf(m)) m = 0.f;
    float s = 0.f;
    for (int n = n0 + t; n < n1; n += 256) {
        float z = expf(e[n] - m);
        e[n] = z;
        s += z;
    }
    red[t] = s;
    __syncthreads();
    for (int o = 128; o > 0; o >>= 1) {
        if (t < o) red[t] += red[t + o];
        __syncthreads();
    }
    float denom = red[0];
    float inv = (denom > 0.f) ? 1.f / denom : 0.f;
    __syncthreads();
    int g = t >> 7, col = t & 127;
    float acc = 0.f;
    for (int n = n0 + g; n < n1; n += 2) {
        acc = fmaf(e[n] * inv, X[(size_t)n * 128 + col], acc);
    }
    red[t] = acc;
    __syncthreads();
    if (t < 128) {
        float r = red[t] + red[t + 128];
        qstar[b * 256 + t] = q[t];
        qstar[b * 256 + 128 + t] = r;
    }
}

// ---------------- final MLP head ----------------
__global__ __launch_bounds__(128) void k_mlp(const float* __restrict__ qstar,
                                             const float* __restrict__ Wl1,
                                             const float* __restrict__ bl1,
                                             const float* __restrict__ Wl2,
                                             const float* __restrict__ bl2,
                                             float* __restrict__ out) {
    int b = blockIdx.x, t = threadIdx.x;
    __shared__ float qs[256];
    __shared__ float hid[128];
    qs[t] = qstar[b * 256 + t];
    qs[128 + t] = qstar[b * 256 + 128 + t];
    __syncthreads();
    float acc = bl1[t];
#pragma unroll 4
    for (int k = 0; k < 256; k++) acc = fmaf(qs[k], Wl1[k * 128 + t], acc);
    hid[t] = fmaxf(acc, 0.f);
    __syncthreads();
    if (t < NUM_CLASSES) {
        float o = bl2[t];
#pragma unroll 4
        for (int k = 0; k < 128; k++) o = fmaf(hid[k], Wl2[k * 10 + t], o);
        out[b * 10 + t] = o;
    }
}

// ---------------- host ----------------

extern "C" void kernel_launch(void* const* d_in, const int* in_sizes, int n_in,
                              void* d_out, int out_size, void* d_ws, size_t ws_size,
                              hipStream_t stream) {
    const float* x    = (const float*)d_in[0];
    const void*  eidx = d_in[1];
    const void*  batr = d_in[2];
    const float* W1   = (const float*)d_in[3];
    const float* b1   = (const float*)d_in[4];
    const float* W2   = (const float*)d_in[5];
    const float* b2   = (const float*)d_in[6];
    const float* Wih  = (const float*)d_in[7];
    const float* Whh  = (const float*)d_in[8];
    const float* bih  = (const float*)d_in[9];
    const float* bhh  = (const float*)d_in[10];
    const float* Wl1  = (const float*)d_in[11];
    const float* bl1  = (const float*)d_in[12];
    const float* Wl2  = (const float*)d_in[13];
    const float* bl2  = (const float*)d_in[14];
    float* out = (float*)d_out;

    char* ws = (char*)d_ws;
    size_t off = 0;
    auto alloc = [&](size_t bytes) {
        size_t r = off;
        off = (off + bytes + 255) & ~(size_t)255;
        return r;
    };
    float* H       = (float*)(ws + alloc((size_t)N_NODES * 128 * 4));
    float* A       = (float*)(ws + alloc((size_t)N_NODES * 128 * 4));
    int*   csr     = (int*)(ws + alloc((size_t)N_EDGES * 4));
    int*   bdata   = (int*)(ws + alloc((size_t)NBUCKETS * BCAP * 4));  // >= 12.8MB
    int*   bcnt    = (int*)(ws + alloc((size_t)NBUCKETS * BCNT_STRIDE * 4));
    int*   batch32 = (int*)(ws + alloc((size_t)N_NODES * 4));
    int*   cnt     = (int*)(ws + alloc((size_t)N_NODES * 4));
    int*   offs    = (int*)(ws + alloc((size_t)(N_NODES + 1) * 4));
    float* dinv    = (float*)(ws + alloc((size_t)N_NODES * 4));
    float* e       = (float*)(ws + alloc((size_t)N_NODES * 4));
    int*   goff    = (int*)(ws + alloc((size_t)(NUM_GRAPHS + 1) * 4));
    float* state   = (float*)(ws + alloc((size_t)(NUM_GRAPHS * 128 * 2 + NUM_GRAPHS * 256) * 4));
    int*   flag    = (int*)(ws + alloc(4));
    if (off > ws_size) return;

    // bf16 copy of gemm output; aliases bdata (dead after k_lscatter).
    // NBUCKETS*BCAP*4 = 12,812,288 B >= N_NODES*128*2 = 12,800,000 B.
    unsigned short* Hb = (unsigned short*)bdata;

    float* h_lstm = state;
    float* c_lstm = state + NUM_GRAPHS * 128;
    float* qstar  = state + NUM_GRAPHS * 256;

    const int B = 256;
    hipMemsetAsync(flag, 0, 4, stream);
    hipMemsetAsync(bcnt, 0, (size_t)NBUCKETS * BCNT_STRIDE * 4, stream);
    hipMemsetAsync(state, 0, (size_t)NUM_GRAPHS * 512 * 4, stream);
    k_detect<<<(4096 + B - 1) / B, B, 0, stream>>>((const int*)eidx, flag, 4096);
    k_cvt_idx<<<(N_NODES + B - 1) / B, B, 0, stream>>>(batr, batch32, N_NODES, flag);
    // CSR build (bucketed, dense writes)
    k_bucket<<<(N_EDGES + B - 1) / B, B, 0, stream>>>(eidx, flag, bcnt, bdata);
    k_goff<<<(N_NODES + B - 1) / B, B, 0, stream>>>(batch32, goff, N_NODES, NUM_GRAPHS);
    k_count<<<NBUCKETS, 256, 0, stream>>>(bcnt, bdata, cnt, dinv);
    k_scan<<<1, 1024, 0, stream>>>(cnt, offs, N_NODES);
    k_lscatter<<<NBUCKETS, 256, 0, stream>>>(bcnt, bdata, offs, csr);
    // GCN conv 1
    k_gemm64<<<(N_NODES + 63) / 64, 256, 0, stream>>>(x, W1, H, Hb, N_NODES);
    k_agg<<<(N_NODES + 3) / 4, 256, 0, stream>>>(H, Hb, dinv, offs, csr, b1, A);
    // GCN conv 2
    k_gemm64<<<(N_NODES + 63) / 64, 256, 0, stream>>>(A, W2, H, Hb, N_NODES);
    k_agg<<<(N_NODES + 3) / 4, 256, 0, stream>>>(H, Hb, dinv, offs, csr, b2, A);
    // Set2Set
    for (int s = 0; s < STEPS; s++) {
        k_lstm<<<NUM_GRAPHS / GPB, 256, 0, stream>>>(qstar, h_lstm, c_lstm, Wih, Whh, bih, bhh);
        k_attn<<<NUM_GRAPHS, 256, 0, stream>>>(A, goff, h_lstm, e, qstar);
    }
    k_mlp<<<NUM_GRAPHS, 128, 0, stream>>>(qstar, Wl1, bl1, Wl2, bl2, out);
}

// Round 5
// 500.078 us; speedup vs baseline: 2.2686x; 1.1428x over previous
//
#include <hip/hip_runtime.h>
#include <hip/hip_bf16.h>
#include <math.h>

#define N_NODES 50000
#define N_EDGES 1600000
#define NUM_GRAPHS 512
#define HIDDEN 128
#define NUM_CLASSES 10
#define STEPS 3

#define NB_SHIFT 6                      // 64 nodes per bucket
#define NODES_PER_B (1 << NB_SHIFT)
#define NBUK ((N_NODES + NODES_PER_B - 1) / NODES_PER_B)   // 782
#define EPB 8192                        // edges per block in the sort
#define NBLK ((N_EDGES + EPB - 1) / EPB)                   // 196
#define MAXR 144                        // attn LDS row cap (max graph ~132)

__device__ inline float bf2f(unsigned short h) {
    union { unsigned int u; float f; } v; v.u = ((unsigned int)h) << 16; return v.f;
}
__device__ inline unsigned short f2bf(float f) {
    union { float f; unsigned int u; } v; v.f = f;
    unsigned int r = (v.u + 0x7FFFu + ((v.u >> 16) & 1u)) >> 16;
    return (unsigned short)r;
}

// ---------------- utility kernels ----------------

// Detect int64 vs int32 storage of index inputs.
__global__ void k_detect(const int* p, int* flag, int npairs) {
    int i = blockIdx.x * blockDim.x + threadIdx.x;
    if (i < npairs) {
        int v = p[2 * i + 1];
        if (v != 0) atomicOr(flag, 1);
    }
}

__global__ void k_cvt_idx(const void* p, int* out, int n, const int* flag) {
    int i = blockIdx.x * blockDim.x + threadIdx.x;
    if (i >= n) return;
    if (*flag) out[i] = ((const int*)p)[i];
    else       out[i] = (int)(((const long long*)p)[i]);
}

// batch is sorted: write graph start offsets by boundary detection.
__global__ void k_goff(const int* batch, int* goff, int n, int ng) {
    int i = blockIdx.x * blockDim.x + threadIdx.x;
    if (i >= n) return;
    int b = batch[i];
    int prev = (i == 0) ? -1 : batch[i - 1];
    for (int g = prev + 1; g <= b; g++) goff[g] = i;
    if (i == n - 1) {
        for (int g = b + 1; g <= ng; g++) goff[g] = n;
    }
}

// Sort pass 1: pack edges + per-block LDS bucket histogram (no global atomics).
__global__ __launch_bounds__(256) void k_pack(const void* eidx, const int* flag,
                                              unsigned int* __restrict__ pdata,
                                              int* __restrict__ histg) {
    __shared__ int lh[NBUK];
    int b = blockIdx.x, t = threadIdx.x;
    for (int i = t; i < NBUK; i += 256) lh[i] = 0;
    __syncthreads();
    int base = b * EPB;
    int end = base + EPB; if (end > N_EDGES) end = N_EDGES;
    bool is32 = (*flag != 0);
    for (int i = base + t; i < end; i += 256) {
        int src, dst;
        if (is32) {
            const int* p = (const int*)eidx;
            src = p[i]; dst = p[N_EDGES + i];
        } else {
            const long long* p = (const long long*)eidx;
            src = (int)p[i]; dst = (int)p[N_EDGES + i];
        }
        pdata[i] = ((unsigned)src << 16) | (unsigned)dst;
        atomicAdd(&lh[dst >> NB_SHIFT], 1);
    }
    __syncthreads();
    for (int i = t; i < NBUK; i += 256) histg[(size_t)b * NBUK + i] = lh[i];
}

// Sort pass 2: per bucket, exclusive scan of counts across blocks + bucket total.
__global__ __launch_bounds__(256) void k_colscan(int* __restrict__ histg,
                                                 int* __restrict__ btot) {
    __shared__ int wsum[4];
    int k = blockIdx.x, t = threadIdx.x;
    int wid = t >> 6, lane = t & 63;
    int v = (t < NBLK) ? histg[(size_t)t * NBUK + k] : 0;
    int x = v;
#pragma unroll
    for (int o = 1; o < 64; o <<= 1) {
        int y = __shfl_up(x, o, 64);
        if (lane >= o) x += y;
    }
    if (lane == 63) wsum[wid] = x;
    __syncthreads();
    int add = 0;
    for (int w = 0; w < wid; w++) add += wsum[w];
    if (t < NBLK) histg[(size_t)t * NBUK + k] = add + x - v;
    if (t == NBLK - 1) btot[k] = add + x;
}

// Single-block exclusive scan via shfl wave-scans (generic n).
__global__ __launch_bounds__(1024) void k_scan(const int* cnt, int* offs, int n) {
    __shared__ int wsum[16];
    __shared__ int carry_sh;
    int t = threadIdx.x, wid = t >> 6, lane = t & 63;
    if (t == 0) { carry_sh = 0; offs[0] = 0; }
    __syncthreads();
    for (int base = 0; base < n; base += 1024) {
        int i = base + t;
        int v = (i < n) ? cnt[i] : 0;
        int x = v;
#pragma unroll
        for (int o = 1; o < 64; o <<= 1) {
            int y = __shfl_up(x, o, 64);
            if (lane >= o) x += y;
        }
        if (lane == 63) wsum[wid] = x;
        __syncthreads();
        if (wid == 0 && lane < 16) {
            int w = wsum[lane];
#pragma unroll
            for (int o = 1; o < 16; o <<= 1) {
                int y = __shfl_up(w, o, 16);
                if (lane >= o) w += y;
            }
            wsum[lane] = w;
        }
        __syncthreads();
        int add = carry_sh + (wid > 0 ? wsum[wid - 1] : 0);
        if (i < n) offs[i + 1] = add + x;
        __syncthreads();
        if (t == 0) carry_sh += wsum[15];
        __syncthreads();
    }
}

// Sort pass 3: place packed edges into bucket-contiguous segments.
__global__ __launch_bounds__(256) void k_place(const unsigned int* __restrict__ pdata,
                                               const int* __restrict__ histg,
                                               const int* __restrict__ bbase,
                                               unsigned int* __restrict__ sdata) {
    __shared__ int lh[NBUK];
    __shared__ int lpre[NBUK];
    int b = blockIdx.x, t = threadIdx.x;
    for (int i = t; i < NBUK; i += 256) {
        lh[i] = 0;
        lpre[i] = bbase[i] + histg[(size_t)b * NBUK + i];
    }
    __syncthreads();
    int base = b * EPB;
    int end = base + EPB; if (end > N_EDGES) end = N_EDGES;
    for (int i = base + t; i < end; i += 256) {
        unsigned p = pdata[i];
        int k = (p & 0xFFFFu) >> NB_SHIFT;
        int pos = atomicAdd(&lh[k], 1);
        sdata[lpre[k] + pos] = p;
    }
}

// Per bucket: count per-node in LDS; write cnt + dinv dense.
__global__ __launch_bounds__(256) void k_count(const unsigned int* __restrict__ sdata,
                                               const int* __restrict__ bbase,
                                               const int* __restrict__ btot,
                                               int* __restrict__ cnt,
                                               float* __restrict__ dinv) {
    __shared__ int lcnt[NODES_PER_B];
    int b = blockIdx.x, t = threadIdx.x;
    if (t < NODES_PER_B) lcnt[t] = 0;
    __syncthreads();
    int s0 = bbase[b], n = btot[b];
    const unsigned int* sd = sdata + s0;
    for (int e = t; e < n; e += 256) {
        atomicAdd(&lcnt[sd[e] & (NODES_PER_B - 1)], 1);
    }
    __syncthreads();
    int node = b * NODES_PER_B + t;
    if (t < NODES_PER_B && node < N_NODES) {
        int c = lcnt[t];
        cnt[node] = c;
        dinv[node] = rsqrtf((float)(c + 1));
    }
}

// Per bucket: scatter src ids into the bucket's contiguous csr range.
__global__ __launch_bounds__(256) void k_lscatter(const unsigned int* __restrict__ sdata,
                                                  const int* __restrict__ bbase,
                                                  const int* __restrict__ btot,
                                                  const int* __restrict__ offs,
                                                  int* __restrict__ csr) {
    __shared__ int lcnt[NODES_PER_B];
    __shared__ int loffs[NODES_PER_B];
    int b = blockIdx.x, t = threadIdx.x;
    if (t < NODES_PER_B) {
        lcnt[t] = 0;
        int node = b * NODES_PER_B + t;
        loffs[t] = (node < N_NODES) ? offs[node] : 0;
    }
    __syncthreads();
    int s0 = bbase[b], n = btot[b];
    const unsigned int* sd = sdata + s0;
    for (int e = t; e < n; e += 256) {
        unsigned p = sd[e];
        int slot = p & (NODES_PER_B - 1);
        int pos = atomicAdd(&lcnt[slot], 1);
        csr[loffs[slot] + pos] = (int)(p >> 16);
    }
}

// ---------------- GEMM: H[n][j] = sum_k X[n][k] * W[k][j], K=N=128 ----------------
// 64 rows/block, 256 threads; thread owns 8 rows x 4 cols. Emits bf16 copy.
__global__ __launch_bounds__(256) void k_gemm64(const float* __restrict__ X,
                                                const float* __restrict__ W,
                                                float* __restrict__ H,
                                                unsigned short* __restrict__ Hb,
                                                int nrows) {
    __shared__ float xs[64][128];
    int t = threadIdx.x;
    int a = t >> 5;
    int j4 = t & 31;
    int row0 = blockIdx.x * 64;
    for (int i = t; i < 64 * 32; i += 256) {
        int rr = i >> 5;
        int c4 = i & 31;
        int r = row0 + rr; if (r >= nrows) r = nrows - 1;
        ((float4*)xs[rr])[c4] = ((const float4*)X)[(size_t)r * 32 + c4];
    }
    __syncthreads();
    float4 acc[8];
#pragma unroll
    for (int i = 0; i < 8; i++) acc[i] = {0.f, 0.f, 0.f, 0.f};
    const float4* wp = (const float4*)W;
#pragma unroll 4
    for (int k = 0; k < 128; k++) {
        float4 w4 = wp[k * 32 + j4];
#pragma unroll
        for (int i = 0; i < 8; i++) {
            float xv = xs[8 * a + i][k];
            acc[i].x = fmaf(xv, w4.x, acc[i].x);
            acc[i].y = fmaf(xv, w4.y, acc[i].y);
            acc[i].z = fmaf(xv, w4.z, acc[i].z);
            acc[i].w = fmaf(xv, w4.w, acc[i].w);
        }
    }
#pragma unroll
    for (int i = 0; i < 8; i++) {
        int r = row0 + 8 * a + i;
        if (r < nrows) {
            ((float4*)H)[(size_t)r * 32 + j4] = acc[i];
            ushort4 b4;
            b4.x = f2bf(acc[i].x); b4.y = f2bf(acc[i].y);
            b4.z = f2bf(acc[i].z); b4.w = f2bf(acc[i].w);
            ((ushort4*)Hb)[(size_t)r * 32 + j4] = b4;
        }
    }
}

// ---------------- GCN aggregate (bf16 neighbor gather, fp32 self) ----------------
__global__ __launch_bounds__(256) void k_agg(const float* __restrict__ H,
                                             const unsigned short* __restrict__ Hb,
                                             const float* __restrict__ dinv,
                                             const int* __restrict__ offs,
                                             const int* __restrict__ csr,
                                             const float* __restrict__ b,
                                             float* __restrict__ out) {
    int wave = (blockIdx.x * blockDim.x + threadIdx.x) >> 6;
    int lane = threadIdx.x & 63;
    if (wave >= N_NODES) return;
    int n = wave;
    int half = lane >> 5;
    int l = lane & 31;
    float di = dinv[n];
    const ushort4* hbp = (const ushort4*)Hb;
    float4 acc = {0.f, 0.f, 0.f, 0.f};
    if (half == 0) {
        float4 hn = ((const float4*)H)[(size_t)n * 32 + l];
        acc.x = di * hn.x; acc.y = di * hn.y; acc.z = di * hn.z; acc.w = di * hn.w;
    }
    int e0 = offs[n], e1 = offs[n + 1];
    int j = e0 + half;
    for (; j + 6 < e1; j += 8) {
        int s0 = csr[j], s1 = csr[j + 2], s2 = csr[j + 4], s3 = csr[j + 6];
        float d0 = dinv[s0], d1 = dinv[s1], d2 = dinv[s2], d3 = dinv[s3];
        ushort4 a0 = hbp[(size_t)s0 * 32 + l];
        ushort4 a1 = hbp[(size_t)s1 * 32 + l];
        ushort4 a2 = hbp[(size_t)s2 * 32 + l];
        ushort4 a3 = hbp[(size_t)s3 * 32 + l];
        acc.x = fmaf(d0, bf2f(a0.x), acc.x); acc.y = fmaf(d0, bf2f(a0.y), acc.y);
        acc.z = fmaf(d0, bf2f(a0.z), acc.z); acc.w = fmaf(d0, bf2f(a0.w), acc.w);
        acc.x = fmaf(d1, bf2f(a1.x), acc.x); acc.y = fmaf(d1, bf2f(a1.y), acc.y);
        acc.z = fmaf(d1, bf2f(a1.z), acc.z); acc.w = fmaf(d1, bf2f(a1.w), acc.w);
        acc.x = fmaf(d2, bf2f(a2.x), acc.x); acc.y = fmaf(d2, bf2f(a2.y), acc.y);
        acc.z = fmaf(d2, bf2f(a2.z), acc.z); acc.w = fmaf(d2, bf2f(a2.w), acc.w);
        acc.x = fmaf(d3, bf2f(a3.x), acc.x); acc.y = fmaf(d3, bf2f(a3.y), acc.y);
        acc.z = fmaf(d3, bf2f(a3.z), acc.z); acc.w = fmaf(d3, bf2f(a3.w), acc.w);
    }
    for (; j < e1; j += 2) {
        int s = csr[j];
        float ds = dinv[s];
        ushort4 hs = hbp[(size_t)s * 32 + l];
        acc.x = fmaf(ds, bf2f(hs.x), acc.x); acc.y = fmaf(ds, bf2f(hs.y), acc.y);
        acc.z = fmaf(ds, bf2f(hs.z), acc.z); acc.w = fmaf(ds, bf2f(hs.w), acc.w);
    }
    acc.x += __shfl_xor(acc.x, 32, 64);
    acc.y += __shfl_xor(acc.y, 32, 64);
    acc.z += __shfl_xor(acc.z, 32, 64);
    acc.w += __shfl_xor(acc.w, 32, 64);
    if (half == 0) {
        const float4* bp = (const float4*)b;
        float4 bb = bp[l];
        float4 o4;
        o4.x = fmaxf(fmaf(di, acc.x, bb.x), 0.f);
        o4.y = fmaxf(fmaf(di, acc.y, bb.y), 0.f);
        o4.z = fmaxf(fmaf(di, acc.z, bb.z), 0.f);
        o4.w = fmaxf(fmaf(di, acc.w, bb.w), 0.f);
        ((float4*)out)[(size_t)n * 32 + l] = o4;
    }
}

// ---------------- Set2Set LSTM step ----------------
#define GPB 8
__global__ __launch_bounds__(256) void k_lstm(const float* __restrict__ qstar,
                                              float* __restrict__ h, float* __restrict__ c,
                                              const float* __restrict__ Wih,
                                              const float* __restrict__ Whh,
                                              const float* __restrict__ bih,
                                              const float* __restrict__ bhh) {
    __shared__ float qs[GPB][256];
    __shared__ float hh[GPB][128];
    __shared__ float gates[GPB][512];
    int g0 = blockIdx.x * GPB;
    int t = threadIdx.x;
    for (int i = t; i < GPB * 256; i += 256) {
        int g = i >> 8, k = i & 255;
        qs[g][k] = qstar[(g0 + g) * 256 + k];
    }
    for (int i = t; i < GPB * 128; i += 256) {
        int g = i >> 7, k = i & 127;
        hh[g][k] = h[(g0 + g) * 128 + k];
    }
    __syncthreads();
    for (int jj = 0; jj < 2; jj++) {
        int j = t + jj * 256;
        float base = bih[j] + bhh[j];
        float acc[GPB];
#pragma unroll
        for (int g = 0; g < GPB; g++) acc[g] = base;
        const float* wi = Wih + j * 256;
        for (int k = 0; k < 256; k++) {
            float w = wi[k];
#pragma unroll
            for (int g = 0; g < GPB; g++) acc[g] = fmaf(w, qs[g][k], acc[g]);
        }
        const float* wh = Whh + j * 128;
        for (int k = 0; k < 128; k++) {
            float w = wh[k];
#pragma unroll
            for (int g = 0; g < GPB; g++) acc[g] = fmaf(w, hh[g][k], acc[g]);
        }
        for (int g = 0; g < GPB; g++) gates[g][j] = acc[g];
    }
    __syncthreads();
    for (int i = t; i < GPB * 128; i += 256) {
        int g = i >> 7, d = i & 127;
        int gg = g0 + g;
        float iv = gates[g][d], fv = gates[g][128 + d];
        float gv = gates[g][256 + d], ov = gates[g][384 + d];
        float si = 1.f / (1.f + expf(-iv));
        float sf = 1.f / (1.f + expf(-fv));
        float so = 1.f / (1.f + expf(-ov));
        float tg = tanhf(gv);
        float cn = sf * c[gg * 128 + d] + si * tg;
        float hn = so * tanhf(cn);
        c[gg * 128 + d] = cn;
        h[gg * 128 + d] = hn;
    }
}

// ---------------- attention: LDS-cached rows (fallback streams) ----------------
__global__ __launch_bounds__(256) void k_attn(const float* __restrict__ X,
                                              const int* __restrict__ goff,
                                              const float* __restrict__ h,
                                              float* __restrict__ eg,
                                              float* __restrict__ qstar) {
    int b = blockIdx.x;
    int t = threadIdx.x;
    int wv = t >> 6, l = t & 63;
    int n0 = goff[b], n1 = goff[b + 1];
    int cnt = n1 - n0;
    __shared__ float rows[MAXR][128];
    __shared__ float q[128];
    __shared__ float ebuf[MAXR];
    __shared__ float red[256];
    __shared__ float wm[4];
    if (t < 128) q[t] = h[b * 128 + t];
    if (cnt <= MAXR) {
        for (int i = t; i < cnt * 32; i += 256) {
            int r = i >> 5, c4 = i & 31;
            ((float4*)rows[r])[c4] = ((const float4*)(X + (size_t)(n0 + r) * 128))[c4];
        }
        __syncthreads();
        const float2* qp = (const float2*)q;
        float2 q2 = qp[l];
        float mloc = -INFINITY;
        for (int n = wv; n < cnt; n += 4) {
            const float2* xp = (const float2*)rows[n];
            float2 x2 = xp[l];
            float p = x2.x * q2.x + x2.y * q2.y;
#pragma unroll
            for (int o = 32; o > 0; o >>= 1) p += __shfl_xor(p, o, 64);
            if (l == 0) ebuf[n] = p;
            mloc = fmaxf(mloc, p);
        }
        if (l == 0) wm[wv] = mloc;
        __syncthreads();
        float m = fmaxf(fmaxf(wm[0], wm[1]), fmaxf(wm[2], wm[3]));
        if (isinf(m)) m = 0.f;
        float s = 0.f;
        for (int n = t; n < cnt; n += 256) {
            float z = expf(ebuf[n] - m);
            ebuf[n] = z;
            s += z;
        }
        red[t] = s;
        __syncthreads();
        for (int o = 128; o > 0; o >>= 1) {
            if (t < o) red[t] += red[t + o];
            __syncthreads();
        }
        float denom = red[0];
        float inv = (denom > 0.f) ? 1.f / denom : 0.f;
        __syncthreads();
        int g = t >> 7, col = t & 127;
        float acc = 0.f;
        for (int n = g; n < cnt; n += 2) {
            acc = fmaf(ebuf[n] * inv, rows[n][col], acc);
        }
        red[t] = acc;
        __syncthreads();
        if (t < 128) {
            float r = red[t] + red[t + 128];
            qstar[b * 256 + t] = q[t];
            qstar[b * 256 + 128 + t] = r;
        }
    } else {
        // streaming fallback (rare)
        __syncthreads();
        const float2* qp = (const float2*)q;
        float2 q2 = qp[l];
        float mloc = -INFINITY;
        for (int n = n0 + wv; n < n1; n += 4) {
            const float2* xp = (const float2*)(X + (size_t)n * 128);
            float2 x2 = xp[l];
            float p = x2.x * q2.x + x2.y * q2.y;
#pragma unroll
            for (int o = 32; o > 0; o >>= 1) p += __shfl_xor(p, o, 64);
            if (l == 0) eg[n] = p;
            mloc = fmaxf(mloc, p);
        }
        if (l == 0) wm[wv] = mloc;
        __syncthreads();
        float m = fmaxf(fmaxf(wm[0], wm[1]), fmaxf(wm[2], wm[3]));
        if (isinf(m)) m = 0.f;
        float s = 0.f;
        for (int n = n0 + t; n < n1; n += 256) {
            float z = expf(eg[n] - m);
            eg[n] = z;
            s += z;
        }
        red[t] = s;
        __syncthreads();
        for (int o = 128; o > 0; o >>= 1) {
            if (t < o) red[t] += red[t + o];
            __syncthreads();
        }
        float denom = red[0];
        float inv = (denom > 0.f) ? 1.f / denom : 0.f;
        __syncthreads();
        int g = t >> 7, col = t & 127;
        float acc = 0.f;
        for (int n = n0 + g; n < n1; n += 2) {
            acc = fmaf(eg[n] * inv, X[(size_t)n * 128 + col], acc);
        }
        red[t] = acc;
        __syncthreads();
        if (t < 128) {
            float r = red[t] + red[t + 128];
            qstar[b * 256 + t] = q[t];
            qstar[b * 256 + 128 + t] = r;
        }
    }
}

// ---------------- final MLP head ----------------
__global__ __launch_bounds__(128) void k_mlp(const float* __restrict__ qstar,
                                             const float* __restrict__ Wl1,
                                             const float* __restrict__ bl1,
                                             const float* __restrict__ Wl2,
                                             const float* __restrict__ bl2,
                                             float* __restrict__ out) {
    int b = blockIdx.x, t = threadIdx.x;
    __shared__ float qs[256];
    __shared__ float hid[128];
    qs[t] = qstar[b * 256 + t];
    qs[128 + t] = qstar[b * 256 + 128 + t];
    __syncthreads();
    float acc = bl1[t];
#pragma unroll 4
    for (int k = 0; k < 256; k++) acc = fmaf(qs[k], Wl1[k * 128 + t], acc);
    hid[t] = fmaxf(acc, 0.f);
    __syncthreads();
    if (t < NUM_CLASSES) {
        float o = bl2[t];
#pragma unroll 4
        for (int k = 0; k < 128; k++) o = fmaf(hid[k], Wl2[k * 10 + t], o);
        out[b * 10 + t] = o;
    }
}

// ---------------- host ----------------

extern "C" void kernel_launch(void* const* d_in, const int* in_sizes, int n_in,
                              void* d_out, int out_size, void* d_ws, size_t ws_size,
                              hipStream_t stream) {
    const float* x    = (const float*)d_in[0];
    const void*  eidx = d_in[1];
    const void*  batr = d_in[2];
    const float* W1   = (const float*)d_in[3];
    const float* b1   = (const float*)d_in[4];
    const float* W2   = (const float*)d_in[5];
    const float* b2   = (const float*)d_in[6];
    const float* Wih  = (const float*)d_in[7];
    const float* Whh  = (const float*)d_in[8];
    const float* bih  = (const float*)d_in[9];
    const float* bhh  = (const float*)d_in[10];
    const float* Wl1  = (const float*)d_in[11];
    const float* bl1  = (const float*)d_in[12];
    const float* Wl2  = (const float*)d_in[13];
    const float* bl2  = (const float*)d_in[14];
    float* out = (float*)d_out;

    char* ws = (char*)d_ws;
    size_t off = 0;
    auto alloc = [&](size_t bytes) {
        size_t r = off;
        off = (off + bytes + 255) & ~(size_t)255;
        return r;
    };
    float* H        = (float*)(ws + alloc((size_t)N_NODES * 128 * 4));
    float* A        = (float*)(ws + alloc((size_t)N_NODES * 128 * 4));
    int*   csr      = (int*)(ws + alloc((size_t)N_EDGES * 4));
    unsigned int* edgebuf = (unsigned int*)(ws + alloc((size_t)2 * N_EDGES * 4));  // pdata+sdata; later Hb
    int*   histg    = (int*)(ws + alloc((size_t)NBLK * NBUK * 4));
    int*   btot     = (int*)(ws + alloc((size_t)NBUK * 4));
    int*   bbase    = (int*)(ws + alloc((size_t)(NBUK + 1) * 4));
    int*   batch32  = (int*)(ws + alloc((size_t)N_NODES * 4));
    int*   cnt      = (int*)(ws + alloc((size_t)N_NODES * 4));
    int*   offs     = (int*)(ws + alloc((size_t)(N_NODES + 1) * 4));
    float* dinv     = (float*)(ws + alloc((size_t)N_NODES * 4));
    float* e        = (float*)(ws + alloc((size_t)N_NODES * 4));
    int*   goff     = (int*)(ws + alloc((size_t)(NUM_GRAPHS + 1) * 4));
    float* state    = (float*)(ws + alloc((size_t)(NUM_GRAPHS * 128 * 2 + NUM_GRAPHS * 256) * 4));
    int*   flag     = (int*)(ws + alloc(4));
    if (off > ws_size) return;

    unsigned int* pdata = edgebuf;
    unsigned int* sdata = edgebuf + N_EDGES;
    // bf16 copy of gemm output; aliases edgebuf (dead after k_lscatter).
    // 2*N_EDGES*4 = 12.8e6 B == N_NODES*128*2 = 12.8e6 B.
    unsigned short* Hb = (unsigned short*)edgebuf;

    float* h_lstm = state;
    float* c_lstm = state + NUM_GRAPHS * 128;
    float* qstar  = state + NUM_GRAPHS * 256;

    const int B = 256;
    hipMemsetAsync(flag, 0, 4, stream);
    hipMemsetAsync(state, 0, (size_t)NUM_GRAPHS * 512 * 4, stream);
    k_detect<<<(4096 + B - 1) / B, B, 0, stream>>>((const int*)eidx, flag, 4096);
    k_cvt_idx<<<(N_NODES + B - 1) / B, B, 0, stream>>>(batr, batch32, N_NODES, flag);
    k_goff<<<(N_NODES + B - 1) / B, B, 0, stream>>>(batch32, goff, N_NODES, NUM_GRAPHS);
    // CSR build: block-local counting sort
    k_pack<<<NBLK, 256, 0, stream>>>(eidx, flag, pdata, histg);
    k_colscan<<<NBUK, 256, 0, stream>>>(histg, btot);
    k_scan<<<1, 1024, 0, stream>>>(btot, bbase, NBUK);
    k_place<<<NBLK, 256, 0, stream>>>(pdata, histg, bbase, sdata);
    k_count<<<NBUK, 256, 0, stream>>>(sdata, bbase, btot, cnt, dinv);
    k_scan<<<1, 1024, 0, stream>>>(cnt, offs, N_NODES);
    k_lscatter<<<NBUK, 256, 0, stream>>>(sdata, bbase, btot, offs, csr);
    // GCN conv 1
    k_gemm64<<<(N_NODES + 63) / 64, 256, 0, stream>>>(x, W1, H, Hb, N_NODES);
    k_agg<<<(N_NODES + 3) / 4, 256, 0, stream>>>(H, Hb, dinv, offs, csr, b1, A);
    // GCN conv 2
    k_gemm64<<<(N_NODES + 63) / 64, 256, 0, stream>>>(A, W2, H, Hb, N_NODES);
    k_agg<<<(N_NODES + 3) / 4, 256, 0, stream>>>(H, Hb, dinv, offs, csr, b2, A);
    // Set2Set
    for (int s = 0; s < STEPS; s++) {
        k_lstm<<<NUM_GRAPHS / GPB, 256, 0, stream>>>(qstar, h_lstm, c_lstm, Wih, Whh, bih, bhh);
        k_attn<<<NUM_GRAPHS, 256, 0, stream>>>(A, goff, h_lstm, e, qstar);
    }
    k_mlp<<<NUM_GRAPHS, 128, 0, stream>>>(qstar, Wl1, bl1, Wl2, bl2, out);
}